// Round 9
// baseline (757.385 us; speedup 1.0000x reference)
//
#include <hip/hip_runtime.h>

constexpr int NROW = 50000;
constexpr int NCOL = 50000;
constexpr int DH   = 128;
constexpr int NTAB = 200000;   // [out_rc(NROW) | in_rc(NCOL) | out_cr(NCOL) | in_cr(NROW)]
constexpr int HB   = 12500;    // bins per section (quarter table), 50 KB LDS
constexpr int HBLK = 64;       // blocks per section

__device__ __forceinline__ float bf_lo(unsigned u) { return __uint_as_float(u << 16); }
__device__ __forceinline__ float bf_hi(unsigned u) { return __uint_as_float(u & 0xffff0000u); }
__device__ __forceinline__ unsigned short f2bf(float f) {   // RNE
    unsigned u = __float_as_uint(f);
    return (unsigned short)((u + 0x7fffu + ((u >> 16) & 1u)) >> 16);
}

// ---- degree histograms via LDS privatization: NO global atomics ----
// grid: 16 sections (4 arrays x 4 quarters) x HBLK blocks, 512 threads
__global__ __launch_bounds__(512) void hist_lds(
        const int* __restrict__ s_rc, const int* __restrict__ d_rc,
        const int* __restrict__ s_cr, const int* __restrict__ d_cr,
        int* __restrict__ partial, int E) {
    __shared__ int h[HB];
    const int sec = blockIdx.x >> 6;           // 0..15
    const int blk = blockIdx.x & (HBLK - 1);
    const int tab = sec >> 2;                  // 0..3 -> array
    const int lo  = (sec & 3) * HB;
    const int* __restrict__ arr = (tab == 0) ? s_rc : (tab == 1) ? d_rc
                                 : (tab == 2) ? s_cr : d_cr;
    for (int i = threadIdx.x; i < HB; i += blockDim.x) h[i] = 0;
    __syncthreads();
    const int stride = HBLK * blockDim.x;
    for (int i = blk * blockDim.x + threadIdx.x; i < E; i += stride) {
        int id = arr[i] - lo;
        if ((unsigned)id < (unsigned)HB) atomicAdd(&h[id], 1);   // LDS atomic, CU-local
    }
    __syncthreads();
    int* __restrict__ out = partial + ((size_t)sec * HBLK + blk) * HB;
    for (int i = threadIdx.x; i < HB; i += blockDim.x) out[i] = h[i];  // plain stores
}

// ---- reduce HBLK partials/section -> cnt + norms ----
__global__ void reduce_norms2(const int* __restrict__ partial, int* __restrict__ cnt,
                              float* __restrict__ norms) {
    int stride = gridDim.x * blockDim.x;
    for (int i = blockIdx.x * blockDim.x + threadIdx.x; i < NTAB; i += stride) {
        int t = i / 50000;
        int r = i - t * 50000;
        int q = r / HB;
        int j = r - q * HB;
        const int* __restrict__ p = partial + ((size_t)(t * 4 + q) * HBLK) * HB + j;
        int s = 0;
#pragma unroll
        for (int b = 0; b < HBLK; ++b) s += p[(size_t)b * HB];
        cnt[i] = s;
        norms[i] = 1.0f / sqrtf((float)max(s, 1));
    }
}

// single-block segmented exclusive scan (1024 threads)
__device__ void scan_dev(const int* __restrict__ cnt, int* __restrict__ ptr, int n) {
    constexpr int NT = 1024;
    const int t = threadIdx.x;
    const int seg = (n + NT - 1) / NT;
    const int lo = t * seg, hi = min(lo + seg, n);
    int sum = 0;
    for (int i = lo; i < hi; ++i) sum += cnt[i];
    __shared__ int buf[NT];
    buf[t] = sum;
    __syncthreads();
    for (int off = 1; off < NT; off <<= 1) {
        int v = (t >= off) ? buf[t - off] : 0;
        __syncthreads();
        buf[t] += v;
        __syncthreads();
    }
    int run = buf[t] - sum;
    for (int i = lo; i < hi; ++i) { ptr[i] = run; run += cnt[i]; }
    if (t == NT - 1) ptr[n] = buf[NT - 1];
}

__global__ void excl_scan2(const int* cA, int* pA, int nA, const int* cB, int* pB, int nB) {
    if (blockIdx.x == 0) scan_dev(cA, pA, nA);
    else                 scan_dev(cB, pB, nB);
}

// ---- convert dst-section partials in place to absolute block start positions ----
__global__ void block_starts(int* __restrict__ partial,
                             const int* __restrict__ ptr_rc, const int* __restrict__ ptr_cr) {
    int stride = gridDim.x * blockDim.x;
    for (int i = blockIdx.x * blockDim.x + threadIdx.x; i < 8 * HB; i += stride) {
        int fsec = i / HB;                 // 0..7 = (rel, quarter)
        int j = i - fsec * HB;
        int rel = fsec >> 2, q = fsec & 3;
        int histsec = rel * 8 + 4 + q;     // tab=(rel*2+1), histsec = tab*4+q
        const int* __restrict__ ptr = rel ? ptr_cr : ptr_rc;
        int run = ptr[q * HB + j];
        int* __restrict__ p = partial + ((size_t)histsec * HBLK) * HB + j;
#pragma unroll
        for (int b = 0; b < HBLK; ++b) {
            int c = p[(size_t)b * HB];
            p[(size_t)b * HB] = run;
            run += c;
        }
    }
}

// ---- CSR fill, atomic-free (LDS offsets), 4-byte packed pair: u16 src | bf16 w<<16 ----
__global__ __launch_bounds__(512) void csr_fill_sorted(
        const int* __restrict__ sA, const int* __restrict__ dA,
        const float* __restrict__ wA, const float* __restrict__ routA, unsigned* __restrict__ pairA,
        const int* __restrict__ sB, const int* __restrict__ dB,
        const float* __restrict__ wB, const float* __restrict__ routB, unsigned* __restrict__ pairB,
        const int* __restrict__ partial, int E) {
    __shared__ int offs[HB];
    const int fsec = blockIdx.x >> 6;
    const int blk  = blockIdx.x & (HBLK - 1);
    const int rel = fsec >> 2, q = fsec & 3;
    const int histsec = rel * 8 + 4 + q;
    const int lo = q * HB;
    const int* __restrict__ src  = rel ? sB : sA;
    const int* __restrict__ dst  = rel ? dB : dA;
    const float* __restrict__ w  = rel ? wB : wA;
    const float* __restrict__ ro = rel ? routB : routA;
    unsigned* __restrict__ pair  = rel ? pairB : pairA;
    const int* __restrict__ bs = partial + ((size_t)histsec * HBLK + blk) * HB;
    for (int i = threadIdx.x; i < HB; i += blockDim.x) offs[i] = bs[i];
    __syncthreads();
    const int stride = HBLK * blockDim.x;
    for (int i = blk * blockDim.x + threadIdx.x; i < E; i += stride) {
        int id = dst[i] - lo;
        if ((unsigned)id < (unsigned)HB) {
            int pos = atomicAdd(&offs[id], 1);            // LDS atomic
            int s = src[i];
            pair[pos] = (unsigned)s | ((unsigned)f2bf(w[i] * ro[s]) << 16);
        }
    }
}

// ---- fp32 -> bf16 feature tables (both in one launch) ----
__global__ void feats_to_bf16(const float4* __restrict__ fr, const float4* __restrict__ fc,
                              ushort4* __restrict__ br, ushort4* __restrict__ bc, int nq) {
    int stride = gridDim.x * blockDim.x;
    for (int i = blockIdx.x * blockDim.x + threadIdx.x; i < 2 * nq; i += stride) {
        bool second = i >= nq;
        int k = second ? i - nq : i;
        float4 v = second ? fc[k] : fr[k];
        ushort4 o;
        o.x = f2bf(v.x); o.y = f2bf(v.y); o.z = f2bf(v.z); o.w = f2bf(v.w);
        if (second) bc[k] = o; else br[k] = o;
    }
}

// ---- D=64 gather: full wave per node, halves interleave edges, 4 edges/half in flight ----
__global__ void gather64_bf16(const unsigned short* __restrict__ h, const int* __restrict__ ptr,
                              const unsigned* __restrict__ pair, float* __restrict__ agg, int n) {
    const int gw   = (blockIdx.x * blockDim.x + threadIdx.x) >> 6;
    const int nw   = (gridDim.x * blockDim.x) >> 6;
    const int lane = threadIdx.x & 63;
    const int half = lane >> 5;
    const int c    = (lane & 31) << 1;          // column pair 0..62
    for (int node = gw; node < n; node += nw) {
        const int beg = ptr[node], end = ptr[node + 1];
        float ax0 = 0.f, ay0 = 0.f, ax1 = 0.f, ay1 = 0.f;
        float ax2 = 0.f, ay2 = 0.f, ax3 = 0.f, ay3 = 0.f;
        int j = beg + half;
        for (; j + 6 < end; j += 8) {
            unsigned p0 = pair[j], p1 = pair[j + 2], p2 = pair[j + 4], p3 = pair[j + 6];
            unsigned h0 = *reinterpret_cast<const unsigned*>(&h[(size_t)(p0 & 0xffffu) * 64 + c]);
            unsigned h1 = *reinterpret_cast<const unsigned*>(&h[(size_t)(p1 & 0xffffu) * 64 + c]);
            unsigned h2 = *reinterpret_cast<const unsigned*>(&h[(size_t)(p2 & 0xffffu) * 64 + c]);
            unsigned h3 = *reinterpret_cast<const unsigned*>(&h[(size_t)(p3 & 0xffffu) * 64 + c]);
            float w0 = bf_hi(p0), w1 = bf_hi(p1), w2 = bf_hi(p2), w3 = bf_hi(p3);
            ax0 = fmaf(bf_lo(h0), w0, ax0); ay0 = fmaf(bf_hi(h0), w0, ay0);
            ax1 = fmaf(bf_lo(h1), w1, ax1); ay1 = fmaf(bf_hi(h1), w1, ay1);
            ax2 = fmaf(bf_lo(h2), w2, ax2); ay2 = fmaf(bf_hi(h2), w2, ay2);
            ax3 = fmaf(bf_lo(h3), w3, ax3); ay3 = fmaf(bf_hi(h3), w3, ay3);
        }
        for (; j < end; j += 2) {
            unsigned p = pair[j];
            unsigned hv = *reinterpret_cast<const unsigned*>(&h[(size_t)(p & 0xffffu) * 64 + c]);
            float w = bf_hi(p);
            ax0 = fmaf(bf_lo(hv), w, ax0); ay0 = fmaf(bf_hi(hv), w, ay0);
        }
        float ax = (ax0 + ax1) + (ax2 + ax3);
        float ay = (ay0 + ay1) + (ay2 + ay3);
        ax += __shfl_xor(ax, 32);
        ay += __shfl_xor(ay, 32);
        if (half == 0) {
            float2 r; r.x = ax; r.y = ay;
            *reinterpret_cast<float2*>(&agg[(size_t)node * 64 + c]) = r;
        }
    }
}

// ---- D=128 gather: full wave per node, lane holds 2 bf16 cols, 4 edges in flight ----
__global__ void gather128_bf16(const unsigned short* __restrict__ h, const int* __restrict__ ptr,
                               const unsigned* __restrict__ pair, float* __restrict__ agg, int n) {
    const int gw   = (blockIdx.x * blockDim.x + threadIdx.x) >> 6;
    const int nw   = (gridDim.x * blockDim.x) >> 6;
    const int lane = threadIdx.x & 63;
    const int c    = lane << 1;                 // column pair 0..126
    for (int node = gw; node < n; node += nw) {
        const int beg = ptr[node], end = ptr[node + 1];
        float ax0 = 0.f, ay0 = 0.f, ax1 = 0.f, ay1 = 0.f;
        float ax2 = 0.f, ay2 = 0.f, ax3 = 0.f, ay3 = 0.f;
        int j = beg;
        for (; j + 3 < end; j += 4) {
            unsigned p0 = pair[j], p1 = pair[j + 1], p2 = pair[j + 2], p3 = pair[j + 3];
            unsigned h0 = *reinterpret_cast<const unsigned*>(&h[(size_t)(p0 & 0xffffu) * 128 + c]);
            unsigned h1 = *reinterpret_cast<const unsigned*>(&h[(size_t)(p1 & 0xffffu) * 128 + c]);
            unsigned h2 = *reinterpret_cast<const unsigned*>(&h[(size_t)(p2 & 0xffffu) * 128 + c]);
            unsigned h3 = *reinterpret_cast<const unsigned*>(&h[(size_t)(p3 & 0xffffu) * 128 + c]);
            float w0 = bf_hi(p0), w1 = bf_hi(p1), w2 = bf_hi(p2), w3 = bf_hi(p3);
            ax0 = fmaf(bf_lo(h0), w0, ax0); ay0 = fmaf(bf_hi(h0), w0, ay0);
            ax1 = fmaf(bf_lo(h1), w1, ax1); ay1 = fmaf(bf_hi(h1), w1, ay1);
            ax2 = fmaf(bf_lo(h2), w2, ax2); ay2 = fmaf(bf_hi(h2), w2, ay2);
            ax3 = fmaf(bf_lo(h3), w3, ax3); ay3 = fmaf(bf_hi(h3), w3, ay3);
        }
        for (; j < end; ++j) {
            unsigned p = pair[j];
            unsigned hv = *reinterpret_cast<const unsigned*>(&h[(size_t)(p & 0xffffu) * 128 + c]);
            float w = bf_hi(p);
            ax0 = fmaf(bf_lo(hv), w, ax0); ay0 = fmaf(bf_hi(hv), w, ay0);
        }
        float2 r;
        r.x = (ax0 + ax1) + (ax2 + ax3);
        r.y = (ay0 + ay1) + (ay2 + ay3);
        *reinterpret_cast<float2*>(&agg[(size_t)node * 128 + c]) = r;
    }
}

// ---- dense epilogue, NO LDS: A-values via wave-uniform (scalar-path) loads ----
// relu(rin*(agg@W)+b); 16 nodes/iter; MEANSUM writes per-block partials.
template <int K, bool MEANSUM, bool OUTBF16>
__global__ void dense_relu_s(const float* __restrict__ agg, const float* __restrict__ rin,
                             const float* __restrict__ W, const float* __restrict__ b,
                             void* __restrict__ outv, float* __restrict__ partial,
                             int n, float invn) {
    constexpr int NB = 16;                      // n % 16 == 0 for both node sets
    const int t = threadIdx.x;                  // one output column each (128)
    const float bias = b[t];
    float acc = 0.f;
    for (int base = blockIdx.x * NB; base < n; base += gridDim.x * NB) {
        float s[NB];
#pragma unroll
        for (int r = 0; r < NB; ++r) s[r] = 0.f;
        for (int k0 = 0; k0 < K; k0 += 4) {
            const float w0 = W[(k0 + 0) * DH + t];
            const float w1 = W[(k0 + 1) * DH + t];
            const float w2 = W[(k0 + 2) * DH + t];
            const float w3 = W[(k0 + 3) * DH + t];
#pragma unroll
            for (int r = 0; r < NB; ++r) {
                const float4 a4 = *reinterpret_cast<const float4*>(&agg[(size_t)(base + r) * K + k0]);
                s[r] = fmaf(a4.x, w0, s[r]);
                s[r] = fmaf(a4.y, w1, s[r]);
                s[r] = fmaf(a4.z, w2, s[r]);
                s[r] = fmaf(a4.w, w3, s[r]);
            }
        }
#pragma unroll
        for (int r = 0; r < NB; ++r) {
            const float v = fmaxf(fmaf(rin[base + r], s[r], bias), 0.f);
            if (MEANSUM) acc += v;
            else if (OUTBF16) ((unsigned short*)outv)[(size_t)(base + r) * DH + t] = f2bf(v);
            else ((float*)outv)[(size_t)(base + r) * DH + t] = v;
        }
    }
    if (MEANSUM) partial[(size_t)blockIdx.x * DH + t] = acc * invn;
}

// ---- sum 2*GRID partial rows into out[0..127] ----
__global__ void reduce_out(const float* __restrict__ partial, float* __restrict__ out, int nrows) {
    const int t = threadIdx.x;                 // 128
    const int per = nrows / gridDim.x;
    const int b0 = blockIdx.x * per;
    float s = 0.f;
    for (int b = b0; b < b0 + per; ++b) s += partial[(size_t)b * DH + t];
    atomicAdd(&out[t], s);
}

extern "C" void kernel_launch(void* const* d_in, const int* in_sizes, int n_in,
                              void* d_out, int out_size, void* d_ws, size_t ws_size,
                              hipStream_t stream) {
    const float* feat_row = (const float*)d_in[0];
    const float* feat_col = (const float*)d_in[1];
    const int*   src_rc   = (const int*)d_in[2];
    const int*   dst_rc   = (const int*)d_in[3];
    const float* w_rc     = (const float*)d_in[4];
    const int*   src_cr   = (const int*)d_in[5];
    const int*   dst_cr   = (const int*)d_in[6];
    const float* w_cr     = (const float*)d_in[7];
    const float* W0_rc    = (const float*)d_in[8];
    const float* b0_rc    = (const float*)d_in[9];
    const float* W0_cr    = (const float*)d_in[10];
    const float* b0_cr    = (const float*)d_in[11];
    const float* W1_rc    = (const float*)d_in[12];
    const float* b1_rc    = (const float*)d_in[13];
    const float* W1_cr    = (const float*)d_in[14];
    const float* b1_cr    = (const float*)d_in[15];
    const int E = in_sizes[2];
    float* out = (float*)d_out;

    // workspace layout (~103 MB); partial hist (51.2 MB) aliases agg_col+agg_row (dead then)
    int*   cnt     = (int*)d_ws;                        // 200000
    float* norms   = (float*)(cnt + 200000);            // 200000 same order as cnt
    int*   ptr_rc  = (int*)(norms + 200000);            // 50004
    int*   ptr_cr  = ptr_rc + 50004;                    // 50004
    unsigned* pair_rc = (unsigned*)(ptr_cr + 50004);    // E (4-byte packed)
    unsigned* pair_cr = pair_rc + E;                    // E
    float* agg_col = (float*)(pair_cr + E);             // NCOL*128
    float* agg_row = agg_col + (size_t)NCOL * DH;       // NROW*128
    unsigned short* bf_row = (unsigned short*)(agg_row + (size_t)NROW * DH); // NROW*64
    unsigned short* bf_col = bf_row + (size_t)NROW * 64;                     // NCOL*64
    unsigned short* h_col1 = bf_col + (size_t)NCOL * 64;                     // NCOL*128
    unsigned short* h_row1 = h_col1 + (size_t)NCOL * DH;                     // NROW*128
    float* partsum = (float*)(h_row1 + (size_t)NROW * DH);                   // 4096*128 fp32
    int*   partial = (int*)agg_col;                     // 16*HBLK*HB ints = 51.2 MB

    float* r_out_rc = norms;
    float* r_in_rc  = norms + NROW;
    float* r_out_cr = norms + NROW + NCOL;
    float* r_in_cr  = norms + NROW + 2 * NCOL;
    int*   c_in_rc  = cnt + NROW;
    int*   c_in_cr  = cnt + NROW + 2 * NCOL;

    // ---- CSR build (shared by both layers) + bf16 feature tables ----
    feats_to_bf16<<<2048, 256, 0, stream>>>((const float4*)feat_row, (const float4*)feat_col,
                                            (ushort4*)bf_row, (ushort4*)bf_col, NROW * 64 / 4);
    hist_lds<<<16 * HBLK, 512, 0, stream>>>(src_rc, dst_rc, src_cr, dst_cr, partial, E);
    reduce_norms2<<<512, 256, 0, stream>>>(partial, cnt, norms);
    excl_scan2<<<2, 1024, 0, stream>>>(c_in_rc, ptr_rc, NCOL, c_in_cr, ptr_cr, NROW);
    block_starts<<<400, 256, 0, stream>>>(partial, ptr_rc, ptr_cr);
    csr_fill_sorted<<<8 * HBLK, 512, 0, stream>>>(
        src_rc, dst_rc, w_rc, r_out_rc, pair_rc,
        src_cr, dst_cr, w_cr, r_out_cr, pair_cr, partial, E);

    // ---- layer 1 ----
    gather64_bf16<<<2048, 256, 0, stream>>>(bf_row, ptr_rc, pair_rc, agg_col, NCOL);
    dense_relu_s<64, false, true><<<2048, 128, 0, stream>>>(agg_col, r_in_rc, W0_rc, b0_rc, h_col1, nullptr, NCOL, 0.f);
    gather64_bf16<<<2048, 256, 0, stream>>>(bf_col, ptr_cr, pair_cr, agg_row, NROW);
    dense_relu_s<64, false, true><<<2048, 128, 0, stream>>>(agg_row, r_in_cr, W0_cr, b0_cr, h_row1, nullptr, NROW, 0.f);

    hipMemsetAsync(out, 0, DH * sizeof(float), stream);

    // ---- layer 2 + fused mean pooling (partials, no atomic storm) ----
    gather128_bf16<<<2048, 256, 0, stream>>>(h_row1, ptr_rc, pair_rc, agg_col, NCOL);
    dense_relu_s<128, true, false><<<2048, 128, 0, stream>>>(agg_col, r_in_rc, W1_rc, b1_rc, nullptr, partsum, NCOL, 1.0f / NCOL);
    gather128_bf16<<<2048, 256, 0, stream>>>(h_col1, ptr_cr, pair_cr, agg_row, NROW);
    dense_relu_s<128, true, false><<<2048, 128, 0, stream>>>(agg_row, r_in_cr, W1_cr, b1_cr, nullptr, partsum + (size_t)2048 * DH, NROW, 1.0f / NROW);
    reduce_out<<<32, 128, 0, stream>>>(partsum, out, 4096);
}

// Round 10
// 435.568 us; speedup vs baseline: 1.7388x; 1.7388x over previous
//
#include <hip/hip_runtime.h>

constexpr int NROW = 50000;
constexpr int NCOL = 50000;
constexpr int DH   = 128;
constexpr int NTAB = 200000;   // [out_rc(NROW) | in_rc(NCOL) | out_cr(NCOL) | in_cr(NROW)]
constexpr int HB   = 12500;    // bins per section (quarter table), 50 KB LDS
constexpr int HBLK = 64;       // blocks per section
constexpr int DGRID = 1250;    // dense grid (3125 strips)

typedef __attribute__((ext_vector_type(8))) short short8;
typedef __attribute__((ext_vector_type(4))) float f32x4;

__device__ __forceinline__ float bf_lo(unsigned u) { return __uint_as_float(u << 16); }
__device__ __forceinline__ float bf_hi(unsigned u) { return __uint_as_float(u & 0xffff0000u); }
__device__ __forceinline__ unsigned short f2bf(float f) {   // RNE
    unsigned u = __float_as_uint(f);
    return (unsigned short)((u + 0x7fffu + ((u >> 16) & 1u)) >> 16);
}

// ---- degree histograms via LDS privatization: NO global atomics ----
__global__ __launch_bounds__(512) void hist_lds(
        const int* __restrict__ s_rc, const int* __restrict__ d_rc,
        const int* __restrict__ s_cr, const int* __restrict__ d_cr,
        int* __restrict__ partial, int E) {
    __shared__ int h[HB];
    const int sec = blockIdx.x >> 6;           // 0..15
    const int blk = blockIdx.x & (HBLK - 1);
    const int tab = sec >> 2;                  // 0..3 -> array
    const int lo  = (sec & 3) * HB;
    const int* __restrict__ arr = (tab == 0) ? s_rc : (tab == 1) ? d_rc
                                 : (tab == 2) ? s_cr : d_cr;
    for (int i = threadIdx.x; i < HB; i += blockDim.x) h[i] = 0;
    __syncthreads();
    const int stride = HBLK * blockDim.x;
    for (int i = blk * blockDim.x + threadIdx.x; i < E; i += stride) {
        int id = arr[i] - lo;
        if ((unsigned)id < (unsigned)HB) atomicAdd(&h[id], 1);   // LDS atomic
    }
    __syncthreads();
    int* __restrict__ out = partial + ((size_t)sec * HBLK + blk) * HB;
    for (int i = threadIdx.x; i < HB; i += blockDim.x) out[i] = h[i];
}

// ---- reduce HBLK partials/section -> cnt + norms ----
__global__ void reduce_norms2(const int* __restrict__ partial, int* __restrict__ cnt,
                              float* __restrict__ norms) {
    int stride = gridDim.x * blockDim.x;
    for (int i = blockIdx.x * blockDim.x + threadIdx.x; i < NTAB; i += stride) {
        int t = i / 50000;
        int r = i - t * 50000;
        int q = r / HB;
        int j = r - q * HB;
        const int* __restrict__ p = partial + ((size_t)(t * 4 + q) * HBLK) * HB + j;
        int s = 0;
#pragma unroll
        for (int b = 0; b < HBLK; ++b) s += p[(size_t)b * HB];
        cnt[i] = s;
        norms[i] = 1.0f / sqrtf((float)max(s, 1));
    }
}

// single-block segmented exclusive scan (1024 threads)
__device__ void scan_dev(const int* __restrict__ cnt, int* __restrict__ ptr, int n) {
    constexpr int NT = 1024;
    const int t = threadIdx.x;
    const int seg = (n + NT - 1) / NT;
    const int lo = t * seg, hi = min(lo + seg, n);
    int sum = 0;
    for (int i = lo; i < hi; ++i) sum += cnt[i];
    __shared__ int buf[NT];
    buf[t] = sum;
    __syncthreads();
    for (int off = 1; off < NT; off <<= 1) {
        int v = (t >= off) ? buf[t - off] : 0;
        __syncthreads();
        buf[t] += v;
        __syncthreads();
    }
    int run = buf[t] - sum;
    for (int i = lo; i < hi; ++i) { ptr[i] = run; run += cnt[i]; }
    if (t == NT - 1) ptr[n] = buf[NT - 1];
}

__global__ void excl_scan2(const int* cA, int* pA, int nA, const int* cB, int* pB, int nB) {
    if (blockIdx.x == 0) scan_dev(cA, pA, nA);
    else                 scan_dev(cB, pB, nB);
}

// ---- convert dst-section partials in place to absolute block start positions ----
__global__ void block_starts(int* __restrict__ partial,
                             const int* __restrict__ ptr_rc, const int* __restrict__ ptr_cr) {
    int stride = gridDim.x * blockDim.x;
    for (int i = blockIdx.x * blockDim.x + threadIdx.x; i < 8 * HB; i += stride) {
        int fsec = i / HB;                 // 0..7 = (rel, quarter)
        int j = i - fsec * HB;
        int rel = fsec >> 2, q = fsec & 3;
        int histsec = rel * 8 + 4 + q;
        const int* __restrict__ ptr = rel ? ptr_cr : ptr_rc;
        int run = ptr[q * HB + j];
        int* __restrict__ p = partial + ((size_t)histsec * HBLK) * HB + j;
#pragma unroll
        for (int b = 0; b < HBLK; ++b) {
            int c = p[(size_t)b * HB];
            p[(size_t)b * HB] = run;
            run += c;
        }
    }
}

// ---- CSR fill, atomic-free (LDS offsets), 4-byte packed pair: u16 src | bf16 w<<16 ----
__global__ __launch_bounds__(512) void csr_fill_sorted(
        const int* __restrict__ sA, const int* __restrict__ dA,
        const float* __restrict__ wA, const float* __restrict__ routA, unsigned* __restrict__ pairA,
        const int* __restrict__ sB, const int* __restrict__ dB,
        const float* __restrict__ wB, const float* __restrict__ routB, unsigned* __restrict__ pairB,
        const int* __restrict__ partial, int E) {
    __shared__ int offs[HB];
    const int fsec = blockIdx.x >> 6;
    const int blk  = blockIdx.x & (HBLK - 1);
    const int rel = fsec >> 2, q = fsec & 3;
    const int histsec = rel * 8 + 4 + q;
    const int lo = q * HB;
    const int* __restrict__ src  = rel ? sB : sA;
    const int* __restrict__ dst  = rel ? dB : dA;
    const float* __restrict__ w  = rel ? wB : wA;
    const float* __restrict__ ro = rel ? routB : routA;
    unsigned* __restrict__ pair  = rel ? pairB : pairA;
    const int* __restrict__ bs = partial + ((size_t)histsec * HBLK + blk) * HB;
    for (int i = threadIdx.x; i < HB; i += blockDim.x) offs[i] = bs[i];
    __syncthreads();
    const int stride = HBLK * blockDim.x;
    for (int i = blk * blockDim.x + threadIdx.x; i < E; i += stride) {
        int id = dst[i] - lo;
        if ((unsigned)id < (unsigned)HB) {
            int pos = atomicAdd(&offs[id], 1);            // LDS atomic
            int s = src[i];
            pair[pos] = (unsigned)s | ((unsigned)f2bf(w[i] * ro[s]) << 16);
        }
    }
}

// ---- fp32 -> bf16 feature tables (both in one launch) ----
__global__ void feats_to_bf16(const float4* __restrict__ fr, const float4* __restrict__ fc,
                              ushort4* __restrict__ br, ushort4* __restrict__ bc, int nq) {
    int stride = gridDim.x * blockDim.x;
    for (int i = blockIdx.x * blockDim.x + threadIdx.x; i < 2 * nq; i += stride) {
        bool second = i >= nq;
        int k = second ? i - nq : i;
        float4 v = second ? fc[k] : fr[k];
        ushort4 o;
        o.x = f2bf(v.x); o.y = f2bf(v.y); o.z = f2bf(v.z); o.w = f2bf(v.w);
        if (second) bc[k] = o; else br[k] = o;
    }
}

// ---- weights -> transposed bf16: wt[n][k] = bf16(W[k][n]) ----
__global__ void prep_weights(const float* __restrict__ W0a, const float* __restrict__ W0b,
                             const float* __restrict__ W1a, const float* __restrict__ W1b,
                             unsigned short* __restrict__ wt) {
    int i = blockIdx.x * blockDim.x + threadIdx.x;
    if (i >= 49152) return;
    const float* W; int K, base, j = i;
    if (i < 8192)       { W = W0a; K = 64;  base = 0; }
    else if (i < 16384) { W = W0b; K = 64;  base = 8192;  j -= 8192; }
    else if (i < 32768) { W = W1a; K = 128; base = 16384; j -= 16384; }
    else                { W = W1b; K = 128; base = 32768; j -= 32768; }
    int n = j / K, k = j - n * K;
    wt[base + j] = f2bf(W[k * DH + n]);
}

// ---- D=64 gather: full wave per node, halves interleave edges, bf16 agg out ----
__global__ void gather64_bf16(const unsigned short* __restrict__ h, const int* __restrict__ ptr,
                              const unsigned* __restrict__ pair, unsigned short* __restrict__ agg, int n) {
    const int gw   = (blockIdx.x * blockDim.x + threadIdx.x) >> 6;
    const int nw   = (gridDim.x * blockDim.x) >> 6;
    const int lane = threadIdx.x & 63;
    const int half = lane >> 5;
    const int c    = (lane & 31) << 1;          // column pair 0..62
    for (int node = gw; node < n; node += nw) {
        const int beg = ptr[node], end = ptr[node + 1];
        float ax0 = 0.f, ay0 = 0.f, ax1 = 0.f, ay1 = 0.f;
        float ax2 = 0.f, ay2 = 0.f, ax3 = 0.f, ay3 = 0.f;
        int j = beg + half;
        for (; j + 6 < end; j += 8) {
            unsigned p0 = pair[j], p1 = pair[j + 2], p2 = pair[j + 4], p3 = pair[j + 6];
            unsigned h0 = *reinterpret_cast<const unsigned*>(&h[(size_t)(p0 & 0xffffu) * 64 + c]);
            unsigned h1 = *reinterpret_cast<const unsigned*>(&h[(size_t)(p1 & 0xffffu) * 64 + c]);
            unsigned h2 = *reinterpret_cast<const unsigned*>(&h[(size_t)(p2 & 0xffffu) * 64 + c]);
            unsigned h3 = *reinterpret_cast<const unsigned*>(&h[(size_t)(p3 & 0xffffu) * 64 + c]);
            float w0 = bf_hi(p0), w1 = bf_hi(p1), w2 = bf_hi(p2), w3 = bf_hi(p3);
            ax0 = fmaf(bf_lo(h0), w0, ax0); ay0 = fmaf(bf_hi(h0), w0, ay0);
            ax1 = fmaf(bf_lo(h1), w1, ax1); ay1 = fmaf(bf_hi(h1), w1, ay1);
            ax2 = fmaf(bf_lo(h2), w2, ax2); ay2 = fmaf(bf_hi(h2), w2, ay2);
            ax3 = fmaf(bf_lo(h3), w3, ax3); ay3 = fmaf(bf_hi(h3), w3, ay3);
        }
        for (; j < end; j += 2) {
            unsigned p = pair[j];
            unsigned hv = *reinterpret_cast<const unsigned*>(&h[(size_t)(p & 0xffffu) * 64 + c]);
            float w = bf_hi(p);
            ax0 = fmaf(bf_lo(hv), w, ax0); ay0 = fmaf(bf_hi(hv), w, ay0);
        }
        float ax = (ax0 + ax1) + (ax2 + ax3);
        float ay = (ay0 + ay1) + (ay2 + ay3);
        ax += __shfl_xor(ax, 32);
        ay += __shfl_xor(ay, 32);
        if (half == 0) {
            unsigned pk = (unsigned)f2bf(ax) | ((unsigned)f2bf(ay) << 16);
            *reinterpret_cast<unsigned*>(&agg[(size_t)node * 64 + c]) = pk;
        }
    }
}

// ---- D=128 gather: full wave per node, lane holds 2 bf16 cols, bf16 agg out ----
__global__ void gather128_bf16(const unsigned short* __restrict__ h, const int* __restrict__ ptr,
                               const unsigned* __restrict__ pair, unsigned short* __restrict__ agg, int n) {
    const int gw   = (blockIdx.x * blockDim.x + threadIdx.x) >> 6;
    const int nw   = (gridDim.x * blockDim.x) >> 6;
    const int lane = threadIdx.x & 63;
    const int c    = lane << 1;                 // column pair 0..126
    for (int node = gw; node < n; node += nw) {
        const int beg = ptr[node], end = ptr[node + 1];
        float ax0 = 0.f, ay0 = 0.f, ax1 = 0.f, ay1 = 0.f;
        float ax2 = 0.f, ay2 = 0.f, ax3 = 0.f, ay3 = 0.f;
        int j = beg;
        for (; j + 3 < end; j += 4) {
            unsigned p0 = pair[j], p1 = pair[j + 1], p2 = pair[j + 2], p3 = pair[j + 3];
            unsigned h0 = *reinterpret_cast<const unsigned*>(&h[(size_t)(p0 & 0xffffu) * 128 + c]);
            unsigned h1 = *reinterpret_cast<const unsigned*>(&h[(size_t)(p1 & 0xffffu) * 128 + c]);
            unsigned h2 = *reinterpret_cast<const unsigned*>(&h[(size_t)(p2 & 0xffffu) * 128 + c]);
            unsigned h3 = *reinterpret_cast<const unsigned*>(&h[(size_t)(p3 & 0xffffu) * 128 + c]);
            float w0 = bf_hi(p0), w1 = bf_hi(p1), w2 = bf_hi(p2), w3 = bf_hi(p3);
            ax0 = fmaf(bf_lo(h0), w0, ax0); ay0 = fmaf(bf_hi(h0), w0, ay0);
            ax1 = fmaf(bf_lo(h1), w1, ax1); ay1 = fmaf(bf_hi(h1), w1, ay1);
            ax2 = fmaf(bf_lo(h2), w2, ax2); ay2 = fmaf(bf_hi(h2), w2, ay2);
            ax3 = fmaf(bf_lo(h3), w3, ax3); ay3 = fmaf(bf_hi(h3), w3, ay3);
        }
        for (; j < end; ++j) {
            unsigned p = pair[j];
            unsigned hv = *reinterpret_cast<const unsigned*>(&h[(size_t)(p & 0xffffu) * 128 + c]);
            float w = bf_hi(p);
            ax0 = fmaf(bf_lo(hv), w, ax0); ay0 = fmaf(bf_hi(hv), w, ay0);
        }
        float rx = (ax0 + ax1) + (ax2 + ax3);
        float ry = (ay0 + ay1) + (ay2 + ay3);
        unsigned pk = (unsigned)f2bf(rx) | ((unsigned)f2bf(ry) << 16);
        *reinterpret_cast<unsigned*>(&agg[(size_t)node * 128 + c]) = pk;
    }
}

// ---- dense epilogue via MFMA 16x16x32 bf16: out = relu(rin*(agg@W)+b) ----
// block = 4 waves; wave w owns output cols [w*32, w*32+32); 16-row strips grid-stride.
// B (transposed weights) held in registers across the whole M loop.
template <int K, bool MEANSUM>
__global__ __launch_bounds__(256) void dense_mfma(
        const unsigned short* __restrict__ agg,   // [n][K] bf16
        const float* __restrict__ rin,
        const unsigned short* __restrict__ wt,    // [128][K] bf16 (pre-transposed)
        const float* __restrict__ b,
        unsigned short* __restrict__ outbf,       // !MEANSUM: [n][128] bf16
        float* __restrict__ partial,               // MEANSUM: [grid][128]
        int n, float invn) {
    constexpr int NCH = K / 32;
    const int wave = threadIdx.x >> 6;
    const int lane = threadIdx.x & 63;
    const int lrow = lane & 15;               // A row within strip / C col within tile
    const int kgrp = lane >> 4;               // 0..3
    const int c0   = wave * 32;               // this wave's 2 col-tiles

    short8 bfr[2][NCH];
#pragma unroll
    for (int t = 0; t < 2; ++t)
#pragma unroll
        for (int ch = 0; ch < NCH; ++ch)
            bfr[t][ch] = *reinterpret_cast<const short8*>(
                &wt[(size_t)(c0 + t * 16 + lrow) * K + ch * 32 + kgrp * 8]);

    const float bias0 = b[c0 + lrow], bias1 = b[c0 + 16 + lrow];
    float acc0 = 0.f, acc1 = 0.f;

    const int nstrip = n >> 4;                 // 50000/16 = 3125 exact
    for (int s = blockIdx.x; s < nstrip; s += gridDim.x) {
        const int r0 = s << 4;
        f32x4 d0 = {0.f, 0.f, 0.f, 0.f}, d1 = {0.f, 0.f, 0.f, 0.f};
#pragma unroll
        for (int ch = 0; ch < NCH; ++ch) {
            short8 af = *reinterpret_cast<const short8*>(
                &agg[(size_t)(r0 + lrow) * K + ch * 32 + kgrp * 8]);
            d0 = __builtin_amdgcn_mfma_f32_16x16x32_bf16(af, bfr[0][ch], d0, 0, 0, 0);
            d1 = __builtin_amdgcn_mfma_f32_16x16x32_bf16(af, bfr[1][ch], d1, 0, 0, 0);
        }
#pragma unroll
        for (int i = 0; i < 4; ++i) {          // C/D: col=lane&15, row=(lane>>4)*4+i
            const int row = r0 + kgrp * 4 + i;
            const float rv = rin[row];
            const float v0 = fmaxf(fmaf(rv, d0[i], bias0), 0.f);
            const float v1 = fmaxf(fmaf(rv, d1[i], bias1), 0.f);
            if (MEANSUM) { acc0 += v0; acc1 += v1; }
            else {
                outbf[(size_t)row * DH + c0 + lrow]      = f2bf(v0);
                outbf[(size_t)row * DH + c0 + 16 + lrow] = f2bf(v1);
            }
        }
    }
    if (MEANSUM) {
        acc0 += __shfl_xor(acc0, 16); acc0 += __shfl_xor(acc0, 32);
        acc1 += __shfl_xor(acc1, 16); acc1 += __shfl_xor(acc1, 32);
        if (kgrp == 0) {
            partial[(size_t)blockIdx.x * DH + c0 + lrow]      = acc0 * invn;
            partial[(size_t)blockIdx.x * DH + c0 + 16 + lrow] = acc1 * invn;
        }
    }
}

// ---- sum partial rows into out[0..127] ----
__global__ void reduce_out(const float* __restrict__ partial, float* __restrict__ out, int nrows) {
    const int t = threadIdx.x;                 // 128
    const int per = nrows / gridDim.x;
    const int b0 = blockIdx.x * per;
    float s = 0.f;
    for (int b = b0; b < b0 + per; ++b) s += partial[(size_t)b * DH + t];
    atomicAdd(&out[t], s);
}

extern "C" void kernel_launch(void* const* d_in, const int* in_sizes, int n_in,
                              void* d_out, int out_size, void* d_ws, size_t ws_size,
                              hipStream_t stream) {
    const float* feat_row = (const float*)d_in[0];
    const float* feat_col = (const float*)d_in[1];
    const int*   src_rc   = (const int*)d_in[2];
    const int*   dst_rc   = (const int*)d_in[3];
    const float* w_rc     = (const float*)d_in[4];
    const int*   src_cr   = (const int*)d_in[5];
    const int*   dst_cr   = (const int*)d_in[6];
    const float* w_cr     = (const float*)d_in[7];
    const float* W0_rc    = (const float*)d_in[8];
    const float* b0_rc    = (const float*)d_in[9];
    const float* W0_cr    = (const float*)d_in[10];
    const float* b0_cr    = (const float*)d_in[11];
    const float* W1_rc    = (const float*)d_in[12];
    const float* b1_rc    = (const float*)d_in[13];
    const float* W1_cr    = (const float*)d_in[14];
    const float* b1_cr    = (const float*)d_in[15];
    const int E = in_sizes[2];
    float* out = (float*)d_out;

    // ---- workspace layout (~80 MB) ----
    int*   cnt     = (int*)d_ws;                        // 200000
    float* norms   = (float*)(cnt + 200000);            // 200000
    int*   ptr_rc  = (int*)(norms + 200000);            // 50004
    int*   ptr_cr  = ptr_rc + 50004;                    // 50004
    unsigned* pair_rc = (unsigned*)(ptr_cr + 50004);    // E
    unsigned* pair_cr = pair_rc + E;                    // E
    unsigned short* agg_col = (unsigned short*)(pair_cr + E);           // 50000*128 bf16
    unsigned short* agg_row = agg_col + (size_t)NCOL * DH;              // 50000*128 bf16
    unsigned short* bf_row  = agg_row + (size_t)NROW * DH;              // 50000*64
    unsigned short* bf_col  = bf_row + (size_t)NROW * 64;               // 50000*64
    unsigned short* h_col1  = bf_col + (size_t)NCOL * 64;               // 50000*128
    unsigned short* h_row1  = h_col1 + (size_t)NCOL * DH;               // 50000*128
    float* partsum = (float*)(h_row1 + (size_t)NROW * DH);              // 2*DGRID*128
    unsigned short* wt = (unsigned short*)(partsum + (size_t)2 * DGRID * DH); // 49152
    // hist/fill partial (51.2 MB) aliases agg_col..h_col1 (all dead during CSR build)
    int* partial = (int*)agg_col;

    float* r_out_rc = norms;
    float* r_in_rc  = norms + NROW;
    float* r_out_cr = norms + NROW + NCOL;
    float* r_in_cr  = norms + NROW + 2 * NCOL;
    int*   c_in_rc  = cnt + NROW;
    int*   c_in_cr  = cnt + NROW + 2 * NCOL;

    unsigned short* wt0_rc = wt;
    unsigned short* wt0_cr = wt + 8192;
    unsigned short* wt1_rc = wt + 16384;
    unsigned short* wt1_cr = wt + 32768;

    // ---- CSR build (partial alias live here) ----
    hist_lds<<<16 * HBLK, 512, 0, stream>>>(src_rc, dst_rc, src_cr, dst_cr, partial, E);
    reduce_norms2<<<512, 256, 0, stream>>>(partial, cnt, norms);
    excl_scan2<<<2, 1024, 0, stream>>>(c_in_rc, ptr_rc, NCOL, c_in_cr, ptr_cr, NROW);
    block_starts<<<400, 256, 0, stream>>>(partial, ptr_rc, ptr_cr);
    csr_fill_sorted<<<8 * HBLK, 512, 0, stream>>>(
        src_rc, dst_rc, w_rc, r_out_rc, pair_rc,
        src_cr, dst_cr, w_cr, r_out_cr, pair_cr, partial, E);

    // ---- bf16 tables (partial now dead) ----
    feats_to_bf16<<<2048, 256, 0, stream>>>((const float4*)feat_row, (const float4*)feat_col,
                                            (ushort4*)bf_row, (ushort4*)bf_col, NROW * 64 / 4);
    prep_weights<<<192, 256, 0, stream>>>(W0_rc, W0_cr, W1_rc, W1_cr, wt);

    // ---- layer 1 ----
    gather64_bf16<<<2048, 256, 0, stream>>>(bf_row, ptr_rc, pair_rc, agg_col, NCOL);
    dense_mfma<64, false><<<DGRID, 256, 0, stream>>>(agg_col, r_in_rc, wt0_rc, b0_rc, h_col1, nullptr, NCOL, 0.f);
    gather64_bf16<<<2048, 256, 0, stream>>>(bf_col, ptr_cr, pair_cr, agg_row, NROW);
    dense_mfma<64, false><<<DGRID, 256, 0, stream>>>(agg_row, r_in_cr, wt0_cr, b0_cr, h_row1, nullptr, NROW, 0.f);

    hipMemsetAsync(out, 0, DH * sizeof(float), stream);

    // ---- layer 2 + fused mean pooling ----
    gather128_bf16<<<2048, 256, 0, stream>>>(h_row1, ptr_rc, pair_rc, agg_col, NCOL);
    dense_mfma<128, true><<<DGRID, 256, 0, stream>>>(agg_col, r_in_rc, wt1_rc, b1_rc, nullptr, partsum, NCOL, 1.0f / NCOL);
    gather128_bf16<<<2048, 256, 0, stream>>>(h_col1, ptr_cr, pair_cr, agg_row, NROW);
    dense_mfma<128, true><<<DGRID, 256, 0, stream>>>(agg_row, r_in_cr, wt1_cr, b1_cr, nullptr, partsum + (size_t)DGRID * DH, NROW, 1.0f / NROW);
    reduce_out<<<50, 128, 0, stream>>>(partsum, out, 2 * DGRID);
}

// Round 11
// 355.329 us; speedup vs baseline: 2.1315x; 1.2258x over previous
//
#include <hip/hip_runtime.h>

constexpr int NROW = 50000;
constexpr int NCOL = 50000;
constexpr int DH   = 128;
constexpr int NTAB = 200000;   // [out_rc(NROW) | in_rc(NCOL) | out_cr(NCOL) | in_cr(NROW)]
constexpr int HB   = 12500;    // bins per section (quarter table), 50 KB LDS
constexpr int HBLK = 64;       // blocks per section
constexpr int DGRID = 1250;    // dense blocks per relation
constexpr int GGRID = 2048;    // gather blocks per relation
constexpr int CH    = 500;     // scan chunk size (100 chunks per table)

typedef __attribute__((ext_vector_type(8))) short short8;
typedef __attribute__((ext_vector_type(4))) float f32x4;

__device__ __forceinline__ float bf_lo(unsigned u) { return __uint_as_float(u << 16); }
__device__ __forceinline__ float bf_hi(unsigned u) { return __uint_as_float(u & 0xffff0000u); }
__device__ __forceinline__ unsigned short f2bf(float f) {   // RNE
    unsigned u = __float_as_uint(f);
    return (unsigned short)((u + 0x7fffu + ((u >> 16) & 1u)) >> 16);
}

// ---- degree histograms via LDS privatization: NO global atomics ----
__global__ __launch_bounds__(512) void hist_lds(
        const int* __restrict__ s_rc, const int* __restrict__ d_rc,
        const int* __restrict__ s_cr, const int* __restrict__ d_cr,
        int* __restrict__ partial, int E) {
    __shared__ int h[HB];
    const int sec = blockIdx.x >> 6;           // 0..15
    const int blk = blockIdx.x & (HBLK - 1);
    const int tab = sec >> 2;                  // 0..3 -> array
    const int lo  = (sec & 3) * HB;
    const int* __restrict__ arr = (tab == 0) ? s_rc : (tab == 1) ? d_rc
                                 : (tab == 2) ? s_cr : d_cr;
    for (int i = threadIdx.x; i < HB; i += blockDim.x) h[i] = 0;
    __syncthreads();
    const int stride = HBLK * blockDim.x;
    for (int i = blk * blockDim.x + threadIdx.x; i < E; i += stride) {
        int id = arr[i] - lo;
        if ((unsigned)id < (unsigned)HB) atomicAdd(&h[id], 1);   // LDS atomic
    }
    __syncthreads();
    int* __restrict__ out = partial + ((size_t)sec * HBLK + blk) * HB;
    for (int i = threadIdx.x; i < HB; i += blockDim.x) out[i] = h[i];
}

// ---- reduce HBLK partials/section -> cnt + norms ----
__global__ void reduce_norms2(const int* __restrict__ partial, int* __restrict__ cnt,
                              float* __restrict__ norms) {
    int stride = gridDim.x * blockDim.x;
    for (int i = blockIdx.x * blockDim.x + threadIdx.x; i < NTAB; i += stride) {
        int t = i / 50000;
        int r = i - t * 50000;
        int q = r / HB;
        int j = r - q * HB;
        const int* __restrict__ p = partial + ((size_t)(t * 4 + q) * HBLK) * HB + j;
        int s = 0;
#pragma unroll
        for (int b = 0; b < HBLK; ++b) s += p[(size_t)b * HB];
        cnt[i] = s;
        norms[i] = 1.0f / sqrtf((float)max(s, 1));
    }
}

// ---- parallel exclusive scan of the two dst-count tables, 3 phases ----
// chunk c in [0,200): table = c/100 (0: in_rc at cnt+NROW, 1: in_cr at cnt+150000)
__global__ __launch_bounds__(256) void scanA(const int* __restrict__ cnt, int* __restrict__ bsum) {
    __shared__ int red[256];
    const int c = blockIdx.x;
    const int* __restrict__ cbl = cnt + ((c >= 100) ? 150000 : 50000);
    const int j0 = (c % 100) * CH;
    int s = 0;
    for (int i = threadIdx.x; i < CH; i += 256) s += cbl[j0 + i];
    red[threadIdx.x] = s;
    __syncthreads();
    for (int off = 128; off > 0; off >>= 1) {
        if (threadIdx.x < off) red[threadIdx.x] += red[threadIdx.x + off];
        __syncthreads();
    }
    if (threadIdx.x == 0) bsum[c] = red[0];
}

__global__ void scanB(const int* __restrict__ bsum, int* __restrict__ cbase) {
    __shared__ int b[200];
    for (int i = threadIdx.x; i < 200; i += blockDim.x) b[i] = bsum[i];
    __syncthreads();
    if (threadIdx.x < 2) {                    // two independent serial scans of 100
        int run = 0;
        const int o = threadIdx.x * 100;
        for (int k = 0; k < 100; ++k) { cbase[o + k] = run; run += b[o + k]; }
    }
}

__global__ __launch_bounds__(512) void scanC(const int* __restrict__ cnt,
                                             const int* __restrict__ cbase,
                                             int* __restrict__ ptr_rc, int* __restrict__ ptr_cr,
                                             int E) {
    __shared__ int buf[512];
    const int c = blockIdx.x;
    const int table = (c >= 100);
    const int* __restrict__ cbl = cnt + (table ? 150000 : 50000);
    int* __restrict__ ptr = table ? ptr_cr : ptr_rc;
    const int j0 = (c % 100) * CH;
    const int t = threadIdx.x;
    const int v = (t < CH) ? cbl[j0 + t] : 0;
    buf[t] = v;
    __syncthreads();
    for (int off = 1; off < 512; off <<= 1) {      // Hillis-Steele inclusive
        int tmp = (t >= off) ? buf[t - off] : 0;
        __syncthreads();
        buf[t] += tmp;
        __syncthreads();
    }
    if (t < CH) ptr[j0 + t] = cbase[c] + buf[t] - v;    // exclusive + chunk base
    if ((c % 100) == 99 && t == 0) ptr[50000] = E;
}

// ---- convert dst-section partials in place to absolute block start positions ----
__global__ void block_starts(int* __restrict__ partial,
                             const int* __restrict__ ptr_rc, const int* __restrict__ ptr_cr) {
    int stride = gridDim.x * blockDim.x;
    for (int i = blockIdx.x * blockDim.x + threadIdx.x; i < 8 * HB; i += stride) {
        int fsec = i / HB;                 // 0..7 = (rel, quarter)
        int j = i - fsec * HB;
        int rel = fsec >> 2, q = fsec & 3;
        int histsec = rel * 8 + 4 + q;
        const int* __restrict__ ptr = rel ? ptr_cr : ptr_rc;
        int run = ptr[q * HB + j];
        int* __restrict__ p = partial + ((size_t)histsec * HBLK) * HB + j;
#pragma unroll
        for (int b = 0; b < HBLK; ++b) {
            int c = p[(size_t)b * HB];
            p[(size_t)b * HB] = run;
            run += c;
        }
    }
}

// ---- CSR fill, atomic-free (LDS offsets), 4-byte packed pair: u16 src | bf16 w<<16 ----
__global__ __launch_bounds__(512) void csr_fill_sorted(
        const int* __restrict__ sA, const int* __restrict__ dA,
        const float* __restrict__ wA, const float* __restrict__ routA, unsigned* __restrict__ pairA,
        const int* __restrict__ sB, const int* __restrict__ dB,
        const float* __restrict__ wB, const float* __restrict__ routB, unsigned* __restrict__ pairB,
        const int* __restrict__ partial, int E) {
    __shared__ int offs[HB];
    const int fsec = blockIdx.x >> 6;
    const int blk  = blockIdx.x & (HBLK - 1);
    const int rel = fsec >> 2, q = fsec & 3;
    const int histsec = rel * 8 + 4 + q;
    const int lo = q * HB;
    const int* __restrict__ src  = rel ? sB : sA;
    const int* __restrict__ dst  = rel ? dB : dA;
    const float* __restrict__ w  = rel ? wB : wA;
    const float* __restrict__ ro = rel ? routB : routA;
    unsigned* __restrict__ pair  = rel ? pairB : pairA;
    const int* __restrict__ bs = partial + ((size_t)histsec * HBLK + blk) * HB;
    for (int i = threadIdx.x; i < HB; i += blockDim.x) offs[i] = bs[i];
    __syncthreads();
    const int stride = HBLK * blockDim.x;
    for (int i = blk * blockDim.x + threadIdx.x; i < E; i += stride) {
        int id = dst[i] - lo;
        if ((unsigned)id < (unsigned)HB) {
            int pos = atomicAdd(&offs[id], 1);            // LDS atomic
            int s = src[i];
            pair[pos] = (unsigned)s | ((unsigned)f2bf(w[i] * ro[s]) << 16);
        }
    }
}

// ---- fp32 -> bf16 feature tables + transposed bf16 weights, one launch ----
__global__ void prep_tables(const float4* __restrict__ fr, const float4* __restrict__ fc,
                            ushort4* __restrict__ br, ushort4* __restrict__ bc, int nq,
                            const float* __restrict__ W0a, const float* __restrict__ W0b,
                            const float* __restrict__ W1a, const float* __restrict__ W1b,
                            unsigned short* __restrict__ wt) {
    const int total = 2 * nq + 49152;
    int stride = gridDim.x * blockDim.x;
    for (int i = blockIdx.x * blockDim.x + threadIdx.x; i < total; i += stride) {
        if (i < 2 * nq) {
            bool second = i >= nq;
            int k = second ? i - nq : i;
            float4 v = second ? fc[k] : fr[k];
            ushort4 o;
            o.x = f2bf(v.x); o.y = f2bf(v.y); o.z = f2bf(v.z); o.w = f2bf(v.w);
            if (second) bc[k] = o; else br[k] = o;
        } else {
            int j = i - 2 * nq;
            const float* W; int K, base;
            if (j < 8192)       { W = W0a; K = 64;  base = 0; }
            else if (j < 16384) { W = W0b; K = 64;  base = 8192;  j -= 8192; }
            else if (j < 32768) { W = W1a; K = 128; base = 16384; j -= 16384; }
            else                { W = W1b; K = 128; base = 32768; j -= 32768; }
            int n = j / K, k = j - n * K;
            wt[base + n * K + k] = f2bf(W[k * DH + n]);
        }
    }
}

// ---- D=64 gather, both relations fused (grid split), bf16 agg out ----
__global__ void gather64_2(const unsigned short* __restrict__ hA, const int* __restrict__ ptrA,
                           const unsigned* __restrict__ pairA, unsigned short* __restrict__ aggA,
                           const unsigned short* __restrict__ hB, const int* __restrict__ ptrB,
                           const unsigned* __restrict__ pairB, unsigned short* __restrict__ aggB,
                           int n) {
    const int rel  = blockIdx.x >= GGRID;
    const int bid  = rel ? blockIdx.x - GGRID : blockIdx.x;
    const unsigned short* __restrict__ h = rel ? hB : hA;
    const int* __restrict__ ptr  = rel ? ptrB : ptrA;
    const unsigned* __restrict__ pair = rel ? pairB : pairA;
    unsigned short* __restrict__ agg  = rel ? aggB : aggA;
    const int gw   = (bid * blockDim.x + threadIdx.x) >> 6;
    const int nw   = (GGRID * blockDim.x) >> 6;
    const int lane = threadIdx.x & 63;
    const int half = lane >> 5;
    const int c    = (lane & 31) << 1;          // column pair 0..62
    for (int node = gw; node < n; node += nw) {
        const int beg = ptr[node], end = ptr[node + 1];
        float ax0 = 0.f, ay0 = 0.f, ax1 = 0.f, ay1 = 0.f;
        float ax2 = 0.f, ay2 = 0.f, ax3 = 0.f, ay3 = 0.f;
        int j = beg + half;
        for (; j + 6 < end; j += 8) {
            unsigned p0 = pair[j], p1 = pair[j + 2], p2 = pair[j + 4], p3 = pair[j + 6];
            unsigned h0 = *reinterpret_cast<const unsigned*>(&h[(size_t)(p0 & 0xffffu) * 64 + c]);
            unsigned h1 = *reinterpret_cast<const unsigned*>(&h[(size_t)(p1 & 0xffffu) * 64 + c]);
            unsigned h2 = *reinterpret_cast<const unsigned*>(&h[(size_t)(p2 & 0xffffu) * 64 + c]);
            unsigned h3 = *reinterpret_cast<const unsigned*>(&h[(size_t)(p3 & 0xffffu) * 64 + c]);
            float w0 = bf_hi(p0), w1 = bf_hi(p1), w2 = bf_hi(p2), w3 = bf_hi(p3);
            ax0 = fmaf(bf_lo(h0), w0, ax0); ay0 = fmaf(bf_hi(h0), w0, ay0);
            ax1 = fmaf(bf_lo(h1), w1, ax1); ay1 = fmaf(bf_hi(h1), w1, ay1);
            ax2 = fmaf(bf_lo(h2), w2, ax2); ay2 = fmaf(bf_hi(h2), w2, ay2);
            ax3 = fmaf(bf_lo(h3), w3, ax3); ay3 = fmaf(bf_hi(h3), w3, ay3);
        }
        for (; j < end; j += 2) {
            unsigned p = pair[j];
            unsigned hv = *reinterpret_cast<const unsigned*>(&h[(size_t)(p & 0xffffu) * 64 + c]);
            float w = bf_hi(p);
            ax0 = fmaf(bf_lo(hv), w, ax0); ay0 = fmaf(bf_hi(hv), w, ay0);
        }
        float ax = (ax0 + ax1) + (ax2 + ax3);
        float ay = (ay0 + ay1) + (ay2 + ay3);
        ax += __shfl_xor(ax, 32);
        ay += __shfl_xor(ay, 32);
        if (half == 0) {
            unsigned pk = (unsigned)f2bf(ax) | ((unsigned)f2bf(ay) << 16);
            *reinterpret_cast<unsigned*>(&agg[(size_t)node * 64 + c]) = pk;
        }
    }
}

// ---- D=128 gather, both relations fused, 8 edges in flight, bf16 agg out ----
__global__ void gather128_2(const unsigned short* __restrict__ hA, const int* __restrict__ ptrA,
                            const unsigned* __restrict__ pairA, unsigned short* __restrict__ aggA,
                            const unsigned short* __restrict__ hB, const int* __restrict__ ptrB,
                            const unsigned* __restrict__ pairB, unsigned short* __restrict__ aggB,
                            int n) {
    const int rel  = blockIdx.x >= GGRID;
    const int bid  = rel ? blockIdx.x - GGRID : blockIdx.x;
    const unsigned short* __restrict__ h = rel ? hB : hA;
    const int* __restrict__ ptr  = rel ? ptrB : ptrA;
    const unsigned* __restrict__ pair = rel ? pairB : pairA;
    unsigned short* __restrict__ agg  = rel ? aggB : aggA;
    const int gw   = (bid * blockDim.x + threadIdx.x) >> 6;
    const int nw   = (GGRID * blockDim.x) >> 6;
    const int lane = threadIdx.x & 63;
    const int c    = lane << 1;                 // column pair 0..126
    for (int node = gw; node < n; node += nw) {
        const int beg = ptr[node], end = ptr[node + 1];
        float ax[8], ay[8];
#pragma unroll
        for (int u = 0; u < 8; ++u) { ax[u] = 0.f; ay[u] = 0.f; }
        int j = beg;
        for (; j + 7 < end; j += 8) {
            unsigned p[8], hv[8];
#pragma unroll
            for (int u = 0; u < 8; ++u) p[u] = pair[j + u];
#pragma unroll
            for (int u = 0; u < 8; ++u)
                hv[u] = *reinterpret_cast<const unsigned*>(&h[(size_t)(p[u] & 0xffffu) * 128 + c]);
#pragma unroll
            for (int u = 0; u < 8; ++u) {
                float w = bf_hi(p[u]);
                ax[u] = fmaf(bf_lo(hv[u]), w, ax[u]);
                ay[u] = fmaf(bf_hi(hv[u]), w, ay[u]);
            }
        }
        for (; j < end; ++j) {
            unsigned p = pair[j];
            unsigned hv = *reinterpret_cast<const unsigned*>(&h[(size_t)(p & 0xffffu) * 128 + c]);
            float w = bf_hi(p);
            ax[0] = fmaf(bf_lo(hv), w, ax[0]); ay[0] = fmaf(bf_hi(hv), w, ay[0]);
        }
        float rx = ((ax[0] + ax[1]) + (ax[2] + ax[3])) + ((ax[4] + ax[5]) + (ax[6] + ax[7]));
        float ry = ((ay[0] + ay[1]) + (ay[2] + ay[3])) + ((ay[4] + ay[5]) + (ay[6] + ay[7]));
        unsigned pk = (unsigned)f2bf(rx) | ((unsigned)f2bf(ry) << 16);
        *reinterpret_cast<unsigned*>(&agg[(size_t)node * 128 + c]) = pk;
    }
}

// ---- dense epilogue via MFMA 16x16x32 bf16, both relations fused ----
template <int K, bool MEANSUM>
__global__ __launch_bounds__(256) void dense_mfma2(
        const unsigned short* __restrict__ aggA, const float* __restrict__ rinA,
        const unsigned short* __restrict__ wtA, const float* __restrict__ bA,
        unsigned short* __restrict__ outA, float* __restrict__ partA,
        const unsigned short* __restrict__ aggB, const float* __restrict__ rinB,
        const unsigned short* __restrict__ wtB, const float* __restrict__ bB,
        unsigned short* __restrict__ outB, float* __restrict__ partB,
        int n, float invn) {
    constexpr int NCH = K / 32;
    const int rel = blockIdx.x >= DGRID;
    const int bid = rel ? blockIdx.x - DGRID : blockIdx.x;
    const unsigned short* __restrict__ agg = rel ? aggB : aggA;
    const float* __restrict__ rin = rel ? rinB : rinA;
    const unsigned short* __restrict__ wt = rel ? wtB : wtA;
    const float* __restrict__ b = rel ? bB : bA;
    unsigned short* __restrict__ outbf = rel ? outB : outA;
    float* __restrict__ partial = rel ? partB : partA;

    const int wave = threadIdx.x >> 6;
    const int lane = threadIdx.x & 63;
    const int lrow = lane & 15;
    const int kgrp = lane >> 4;
    const int c0   = wave * 32;

    short8 bfr[2][NCH];
#pragma unroll
    for (int t = 0; t < 2; ++t)
#pragma unroll
        for (int ch = 0; ch < NCH; ++ch)
            bfr[t][ch] = *reinterpret_cast<const short8*>(
                &wt[(size_t)(c0 + t * 16 + lrow) * K + ch * 32 + kgrp * 8]);

    const float bias0 = b[c0 + lrow], bias1 = b[c0 + 16 + lrow];
    float acc0 = 0.f, acc1 = 0.f;

    const int nstrip = n >> 4;                 // 3125
    for (int s = bid; s < nstrip; s += DGRID) {
        const int r0 = s << 4;
        f32x4 d0 = {0.f, 0.f, 0.f, 0.f}, d1 = {0.f, 0.f, 0.f, 0.f};
#pragma unroll
        for (int ch = 0; ch < NCH; ++ch) {
            short8 af = *reinterpret_cast<const short8*>(
                &agg[(size_t)(r0 + lrow) * K + ch * 32 + kgrp * 8]);
            d0 = __builtin_amdgcn_mfma_f32_16x16x32_bf16(af, bfr[0][ch], d0, 0, 0, 0);
            d1 = __builtin_amdgcn_mfma_f32_16x16x32_bf16(af, bfr[1][ch], d1, 0, 0, 0);
        }
#pragma unroll
        for (int i = 0; i < 4; ++i) {          // C/D: col=lane&15, row=(lane>>4)*4+i
            const int row = r0 + kgrp * 4 + i;
            const float rv = rin[row];
            const float v0 = fmaxf(fmaf(rv, d0[i], bias0), 0.f);
            const float v1 = fmaxf(fmaf(rv, d1[i], bias1), 0.f);
            if (MEANSUM) { acc0 += v0; acc1 += v1; }
            else {
                outbf[(size_t)row * DH + c0 + lrow]      = f2bf(v0);
                outbf[(size_t)row * DH + c0 + 16 + lrow] = f2bf(v1);
            }
        }
    }
    if (MEANSUM) {
        acc0 += __shfl_xor(acc0, 16); acc0 += __shfl_xor(acc0, 32);
        acc1 += __shfl_xor(acc1, 16); acc1 += __shfl_xor(acc1, 32);
        if (kgrp == 0) {
            partial[(size_t)bid * DH + c0 + lrow]      = acc0 * invn;
            partial[(size_t)bid * DH + c0 + 16 + lrow] = acc1 * invn;
        }
    }
}

// ---- sum partial rows into out[0..127] ----
__global__ void reduce_out(const float* __restrict__ partial, float* __restrict__ out, int nrows) {
    const int t = threadIdx.x;                 // 128
    const int per = nrows / gridDim.x;
    const int b0 = blockIdx.x * per;
    float s = 0.f;
    for (int b = b0; b < b0 + per; ++b) s += partial[(size_t)b * DH + t];
    atomicAdd(&out[t], s);
}

extern "C" void kernel_launch(void* const* d_in, const int* in_sizes, int n_in,
                              void* d_out, int out_size, void* d_ws, size_t ws_size,
                              hipStream_t stream) {
    const float* feat_row = (const float*)d_in[0];
    const float* feat_col = (const float*)d_in[1];
    const int*   src_rc   = (const int*)d_in[2];
    const int*   dst_rc   = (const int*)d_in[3];
    const float* w_rc     = (const float*)d_in[4];
    const int*   src_cr   = (const int*)d_in[5];
    const int*   dst_cr   = (const int*)d_in[6];
    const float* w_cr     = (const float*)d_in[7];
    const float* W0_rc    = (const float*)d_in[8];
    const float* b0_rc    = (const float*)d_in[9];
    const float* W0_cr    = (const float*)d_in[10];
    const float* b0_cr    = (const float*)d_in[11];
    const float* W1_rc    = (const float*)d_in[12];
    const float* b1_rc    = (const float*)d_in[13];
    const float* W1_cr    = (const float*)d_in[14];
    const float* b1_cr    = (const float*)d_in[15];
    const int E = in_sizes[2];
    float* out = (float*)d_out;

    // ---- workspace layout (~80 MB) ----
    int*   cnt     = (int*)d_ws;                        // 200000
    float* norms   = (float*)(cnt + 200000);            // 200000
    int*   ptr_rc  = (int*)(norms + 200000);            // 50004
    int*   ptr_cr  = ptr_rc + 50004;                    // 50004
    int*   bsum    = ptr_cr + 50004;                    // 200
    int*   cbase   = bsum + 200;                        // 200
    unsigned* pair_rc = (unsigned*)(cbase + 216);       // E
    unsigned* pair_cr = pair_rc + E;                    // E
    unsigned short* agg_col = (unsigned short*)(pair_cr + E);           // 50000*128 bf16
    unsigned short* agg_row = agg_col + (size_t)NCOL * DH;              // 50000*128 bf16
    unsigned short* bf_row  = agg_row + (size_t)NROW * DH;              // 50000*64
    unsigned short* bf_col  = bf_row + (size_t)NROW * 64;               // 50000*64
    unsigned short* h_col1  = bf_col + (size_t)NCOL * 64;               // 50000*128
    unsigned short* h_row1  = h_col1 + (size_t)NCOL * DH;               // 50000*128
    float* partsum = (float*)(h_row1 + (size_t)NROW * DH);              // 2*DGRID*128
    unsigned short* wt = (unsigned short*)(partsum + (size_t)2 * DGRID * DH); // 49152
    // hist/fill partial (51.2 MB) aliases agg_col..h_col1 (all dead during CSR build)
    int* partial = (int*)agg_col;

    float* r_out_rc = norms;
    float* r_in_rc  = norms + NROW;
    float* r_out_cr = norms + NROW + NCOL;
    float* r_in_cr  = norms + NROW + 2 * NCOL;

    unsigned short* wt0_rc = wt;
    unsigned short* wt0_cr = wt + 8192;
    unsigned short* wt1_rc = wt + 16384;
    unsigned short* wt1_cr = wt + 32768;

    // ---- CSR build (partial alias live here) ----
    hist_lds<<<16 * HBLK, 512, 0, stream>>>(src_rc, dst_rc, src_cr, dst_cr, partial, E);
    reduce_norms2<<<512, 256, 0, stream>>>(partial, cnt, norms);
    scanA<<<200, 256, 0, stream>>>(cnt, bsum);
    scanB<<<1, 256, 0, stream>>>(bsum, cbase);
    scanC<<<200, 512, 0, stream>>>(cnt, cbase, ptr_rc, ptr_cr, E);
    block_starts<<<400, 256, 0, stream>>>(partial, ptr_rc, ptr_cr);
    csr_fill_sorted<<<8 * HBLK, 512, 0, stream>>>(
        src_rc, dst_rc, w_rc, r_out_rc, pair_rc,
        src_cr, dst_cr, w_cr, r_out_cr, pair_cr, partial, E);

    // ---- bf16 tables + weights (partial now dead) ----
    prep_tables<<<2048, 256, 0, stream>>>((const float4*)feat_row, (const float4*)feat_col,
                                          (ushort4*)bf_row, (ushort4*)bf_col, NROW * 64 / 4,
                                          W0_rc, W0_cr, W1_rc, W1_cr, wt);

    // ---- layer 1 (both relations fused per stage) ----
    gather64_2<<<2 * GGRID, 256, 0, stream>>>(bf_row, ptr_rc, pair_rc, agg_col,
                                              bf_col, ptr_cr, pair_cr, agg_row, NCOL);
    dense_mfma2<64, false><<<2 * DGRID, 256, 0, stream>>>(
        agg_col, r_in_rc, wt0_rc, b0_rc, h_col1, nullptr,
        agg_row, r_in_cr, wt0_cr, b0_cr, h_row1, nullptr, NCOL, 0.f);

    hipMemsetAsync(out, 0, DH * sizeof(float), stream);

    // ---- layer 2 + fused mean pooling ----
    gather128_2<<<2 * GGRID, 256, 0, stream>>>(h_row1, ptr_rc, pair_rc, agg_col,
                                               h_col1, ptr_cr, pair_cr, agg_row, NCOL);
    dense_mfma2<128, true><<<2 * DGRID, 256, 0, stream>>>(
        agg_col, r_in_rc, wt1_rc, b1_rc, nullptr, partsum,
        agg_row, r_in_cr, wt1_cr, b1_cr, nullptr, partsum + (size_t)DGRID * DH,
        NCOL, 1.0f / NCOL);
    reduce_out<<<50, 128, 0, stream>>>(partsum, out, 2 * DGRID);
}

// Round 12
// 335.415 us; speedup vs baseline: 2.2581x; 1.0594x over previous
//
#include <hip/hip_runtime.h>
#include <stdint.h>

constexpr int NROW = 50000;
constexpr int NCOL = 50000;
constexpr int DH   = 128;
constexpr int NTAB = 200000;   // [out_rc(NROW) | in_rc(NCOL) | out_cr(NCOL) | in_cr(NROW)]
constexpr int HB   = 12500;    // bins per section (quarter table), 50 KB LDS
constexpr int HBLK = 64;       // blocks per section
constexpr int DGRID = 1250;    // dense blocks per relation
constexpr int GGRID = 2048;    // gather blocks per relation
constexpr int CH    = 500;     // scan chunk size (100 chunks per table)

typedef __attribute__((ext_vector_type(8))) short short8;
typedef __attribute__((ext_vector_type(4))) float f32x4;
typedef __attribute__((ext_vector_type(2))) float f32x2;

__device__ __forceinline__ float bf_hi(unsigned u) { return __uint_as_float(u & 0xffff0000u); }
__device__ __forceinline__ unsigned short f2bf(float f) {   // RNE
    unsigned u = __float_as_uint(f);
    return (unsigned short)((u + 0x7fffu + ((u >> 16) & 1u)) >> 16);
}

// ---- fp8 OCP e4m3fn encode (RNE, clamp 448, subnormal-aware) ----
__device__ __forceinline__ unsigned char f2fp8(float f) {
    unsigned b = __float_as_uint(f);
    unsigned s = (b >> 24) & 0x80u;
    unsigned mag = b & 0x7fffffffu;
    if (mag >= 0x43e00000u) return (unsigned char)(s | 0x7eu);   // clamp to ±448
    unsigned r = mag + 0x7ffffu + ((mag >> 20) & 1u);
    int e = (int)(r >> 23) - 120;
    if (e < 1) {                                                  // subnormal: m * 2^-9
        float af = __uint_as_float(mag);
        unsigned m = (unsigned)(af * 512.f + 0.5f);
        if (m > 8u) m = 8u;                                       // 8 == min normal 2^-6
        return (unsigned char)(s | m);
    }
    return (unsigned char)(s | (unsigned)(e << 3) | ((r >> 20) & 7u));
}

// ---- fp8 x2 decode (HW cvt if available) ----
#if defined(__has_builtin) && __has_builtin(__builtin_amdgcn_cvt_pk_f32_fp8)
__device__ __forceinline__ f32x2 fp8x2f(unsigned v) {
    return __builtin_amdgcn_cvt_pk_f32_fp8((int)v, false);
}
#else
__device__ __forceinline__ float fp8_1(unsigned u) {
    unsigned s = (u & 0x80u) << 24, em = u & 0x7fu;
    if (em >= 8u) return __uint_as_float(s | ((em + 960u) << 20));
    float v = (float)em * 0.001953125f;                           // m * 2^-9
    return (u & 0x80u) ? -v : v;
}
__device__ __forceinline__ f32x2 fp8x2f(unsigned v) {
    f32x2 r; r.x = fp8_1(v & 0xffu); r.y = fp8_1((v >> 8) & 0xffu); return r;
}
#endif

// ---- degree histograms via LDS privatization: NO global atomics ----
__global__ __launch_bounds__(512) void hist_lds(
        const int* __restrict__ s_rc, const int* __restrict__ d_rc,
        const int* __restrict__ s_cr, const int* __restrict__ d_cr,
        int* __restrict__ partial, int E) {
    __shared__ int h[HB];
    const int sec = blockIdx.x >> 6;           // 0..15
    const int blk = blockIdx.x & (HBLK - 1);
    const int tab = sec >> 2;                  // 0..3 -> array
    const int lo  = (sec & 3) * HB;
    const int* __restrict__ arr = (tab == 0) ? s_rc : (tab == 1) ? d_rc
                                 : (tab == 2) ? s_cr : d_cr;
    for (int i = threadIdx.x; i < HB; i += blockDim.x) h[i] = 0;
    __syncthreads();
    const int stride = HBLK * blockDim.x;
    for (int i = blk * blockDim.x + threadIdx.x; i < E; i += stride) {
        int id = arr[i] - lo;
        if ((unsigned)id < (unsigned)HB) atomicAdd(&h[id], 1);   // LDS atomic
    }
    __syncthreads();
    int* __restrict__ out = partial + ((size_t)sec * HBLK + blk) * HB;
    for (int i = threadIdx.x; i < HB; i += blockDim.x) out[i] = h[i];
}

// ---- reduce HBLK partials/section -> cnt + norms ----
__global__ void reduce_norms2(const int* __restrict__ partial, int* __restrict__ cnt,
                              float* __restrict__ norms) {
    int stride = gridDim.x * blockDim.x;
    for (int i = blockIdx.x * blockDim.x + threadIdx.x; i < NTAB; i += stride) {
        int t = i / 50000;
        int r = i - t * 50000;
        int q = r / HB;
        int j = r - q * HB;
        const int* __restrict__ p = partial + ((size_t)(t * 4 + q) * HBLK) * HB + j;
        int s = 0;
#pragma unroll
        for (int b = 0; b < HBLK; ++b) s += p[(size_t)b * HB];
        cnt[i] = s;
        norms[i] = 1.0f / sqrtf((float)max(s, 1));
    }
}

// ---- parallel exclusive scan of the two dst-count tables, 3 phases ----
__global__ __launch_bounds__(256) void scanA(const int* __restrict__ cnt, int* __restrict__ bsum) {
    __shared__ int red[256];
    const int c = blockIdx.x;
    const int* __restrict__ cbl = cnt + ((c >= 100) ? 150000 : 50000);
    const int j0 = (c % 100) * CH;
    int s = 0;
    for (int i = threadIdx.x; i < CH; i += 256) s += cbl[j0 + i];
    red[threadIdx.x] = s;
    __syncthreads();
    for (int off = 128; off > 0; off >>= 1) {
        if (threadIdx.x < off) red[threadIdx.x] += red[threadIdx.x + off];
        __syncthreads();
    }
    if (threadIdx.x == 0) bsum[c] = red[0];
}

__global__ void scanB(const int* __restrict__ bsum, int* __restrict__ cbase) {
    __shared__ int b[200];
    for (int i = threadIdx.x; i < 200; i += blockDim.x) b[i] = bsum[i];
    __syncthreads();
    if (threadIdx.x < 2) {
        int run = 0;
        const int o = threadIdx.x * 100;
        for (int k = 0; k < 100; ++k) { cbase[o + k] = run; run += b[o + k]; }
    }
}

__global__ __launch_bounds__(512) void scanC(const int* __restrict__ cnt,
                                             const int* __restrict__ cbase,
                                             int* __restrict__ ptr_rc, int* __restrict__ ptr_cr,
                                             int E) {
    __shared__ int buf[512];
    const int c = blockIdx.x;
    const int table = (c >= 100);
    const int* __restrict__ cbl = cnt + (table ? 150000 : 50000);
    int* __restrict__ ptr = table ? ptr_cr : ptr_rc;
    const int j0 = (c % 100) * CH;
    const int t = threadIdx.x;
    const int v = (t < CH) ? cbl[j0 + t] : 0;
    buf[t] = v;
    __syncthreads();
    for (int off = 1; off < 512; off <<= 1) {
        int tmp = (t >= off) ? buf[t - off] : 0;
        __syncthreads();
        buf[t] += tmp;
        __syncthreads();
    }
    if (t < CH) ptr[j0 + t] = cbase[c] + buf[t] - v;
    if ((c % 100) == 99 && t == 0) ptr[50000] = E;
}

// ---- convert dst-section partials in place to absolute block start positions ----
__global__ void block_starts(int* __restrict__ partial,
                             const int* __restrict__ ptr_rc, const int* __restrict__ ptr_cr) {
    int stride = gridDim.x * blockDim.x;
    for (int i = blockIdx.x * blockDim.x + threadIdx.x; i < 8 * HB; i += stride) {
        int fsec = i / HB;                 // 0..7 = (rel, quarter)
        int j = i - fsec * HB;
        int rel = fsec >> 2, q = fsec & 3;
        int histsec = rel * 8 + 4 + q;
        const int* __restrict__ ptr = rel ? ptr_cr : ptr_rc;
        int run = ptr[q * HB + j];
        int* __restrict__ p = partial + ((size_t)histsec * HBLK) * HB + j;
#pragma unroll
        for (int b = 0; b < HBLK; ++b) {
            int c = p[(size_t)b * HB];
            p[(size_t)b * HB] = run;
            run += c;
        }
    }
}

// ---- CSR fill, atomic-free (LDS offsets), 4-byte packed pair: u16 src | bf16 w<<16 ----
__global__ __launch_bounds__(512) void csr_fill_sorted(
        const int* __restrict__ sA, const int* __restrict__ dA,
        const float* __restrict__ wA, const float* __restrict__ routA, unsigned* __restrict__ pairA,
        const int* __restrict__ sB, const int* __restrict__ dB,
        const float* __restrict__ wB, const float* __restrict__ routB, unsigned* __restrict__ pairB,
        const int* __restrict__ partial, int E) {
    __shared__ int offs[HB];
    const int fsec = blockIdx.x >> 6;
    const int blk  = blockIdx.x & (HBLK - 1);
    const int rel = fsec >> 2, q = fsec & 3;
    const int histsec = rel * 8 + 4 + q;
    const int lo = q * HB;
    const int* __restrict__ src  = rel ? sB : sA;
    const int* __restrict__ dst  = rel ? dB : dA;
    const float* __restrict__ w  = rel ? wB : wA;
    const float* __restrict__ ro = rel ? routB : routA;
    unsigned* __restrict__ pair  = rel ? pairB : pairA;
    const int* __restrict__ bs = partial + ((size_t)histsec * HBLK + blk) * HB;
    for (int i = threadIdx.x; i < HB; i += blockDim.x) offs[i] = bs[i];
    __syncthreads();
    const int stride = HBLK * blockDim.x;
    for (int i = blk * blockDim.x + threadIdx.x; i < E; i += stride) {
        int id = dst[i] - lo;
        if ((unsigned)id < (unsigned)HB) {
            int pos = atomicAdd(&offs[id], 1);            // LDS atomic
            int s = src[i];
            pair[pos] = (unsigned)s | ((unsigned)f2bf(w[i] * ro[s]) << 16);
        }
    }
}

// ---- fp32 -> fp8 feature tables + transposed bf16 weights, one launch ----
__global__ void prep_tables(const float4* __restrict__ fr, const float4* __restrict__ fc,
                            unsigned* __restrict__ f8r, unsigned* __restrict__ f8c, int nq,
                            const float* __restrict__ W0a, const float* __restrict__ W0b,
                            const float* __restrict__ W1a, const float* __restrict__ W1b,
                            unsigned short* __restrict__ wt) {
    const int total = 2 * nq + 49152;
    int stride = gridDim.x * blockDim.x;
    for (int i = blockIdx.x * blockDim.x + threadIdx.x; i < total; i += stride) {
        if (i < 2 * nq) {
            bool second = i >= nq;
            int k = second ? i - nq : i;
            float4 v = second ? fc[k] : fr[k];
            unsigned o = (unsigned)f2fp8(v.x) | ((unsigned)f2fp8(v.y) << 8)
                       | ((unsigned)f2fp8(v.z) << 16) | ((unsigned)f2fp8(v.w) << 24);
            if (second) f8c[k] = o; else f8r[k] = o;
        } else {
            int j = i - 2 * nq;
            const float* W; int K, base;
            if (j < 8192)       { W = W0a; K = 64;  base = 0; }
            else if (j < 16384) { W = W0b; K = 64;  base = 8192;  j -= 8192; }
            else if (j < 32768) { W = W1a; K = 128; base = 16384; j -= 16384; }
            else                { W = W1b; K = 128; base = 32768; j -= 32768; }
            int n = j / K, k = j - n * K;
            wt[base + n * K + k] = f2bf(W[k * DH + n]);
        }
    }
}

// ---- D=64 gather from fp8 tables, both relations fused, bf16 agg out ----
__global__ void gather64_2(const uint8_t* __restrict__ hA, const int* __restrict__ ptrA,
                           const unsigned* __restrict__ pairA, unsigned short* __restrict__ aggA,
                           const uint8_t* __restrict__ hB, const int* __restrict__ ptrB,
                           const unsigned* __restrict__ pairB, unsigned short* __restrict__ aggB,
                           int n) {
    const int rel  = blockIdx.x >= GGRID;
    const int bid  = rel ? blockIdx.x - GGRID : blockIdx.x;
    const uint8_t* __restrict__ h = rel ? hB : hA;
    const int* __restrict__ ptr  = rel ? ptrB : ptrA;
    const unsigned* __restrict__ pair = rel ? pairB : pairA;
    unsigned short* __restrict__ agg  = rel ? aggB : aggA;
    const int gw   = (bid * blockDim.x + threadIdx.x) >> 6;
    const int nw   = (GGRID * blockDim.x) >> 6;
    const int lane = threadIdx.x & 63;
    const int half = lane >> 5;
    const int c    = (lane & 31) << 1;          // column pair 0..62 (byte offset too)
    for (int node = gw; node < n; node += nw) {
        const int beg = ptr[node], end = ptr[node + 1];
        float ax0 = 0.f, ay0 = 0.f, ax1 = 0.f, ay1 = 0.f;
        float ax2 = 0.f, ay2 = 0.f, ax3 = 0.f, ay3 = 0.f;
        int j = beg + half;
        for (; j + 6 < end; j += 8) {
            unsigned p0 = pair[j], p1 = pair[j + 2], p2 = pair[j + 4], p3 = pair[j + 6];
            unsigned h0 = *reinterpret_cast<const unsigned short*>(&h[(size_t)(p0 & 0xffffu) * 64 + c]);
            unsigned h1 = *reinterpret_cast<const unsigned short*>(&h[(size_t)(p1 & 0xffffu) * 64 + c]);
            unsigned h2 = *reinterpret_cast<const unsigned short*>(&h[(size_t)(p2 & 0xffffu) * 64 + c]);
            unsigned h3 = *reinterpret_cast<const unsigned short*>(&h[(size_t)(p3 & 0xffffu) * 64 + c]);
            f32x2 d0 = fp8x2f(h0), d1 = fp8x2f(h1), d2 = fp8x2f(h2), d3 = fp8x2f(h3);
            float w0 = bf_hi(p0), w1 = bf_hi(p1), w2 = bf_hi(p2), w3 = bf_hi(p3);
            ax0 = fmaf(d0.x, w0, ax0); ay0 = fmaf(d0.y, w0, ay0);
            ax1 = fmaf(d1.x, w1, ax1); ay1 = fmaf(d1.y, w1, ay1);
            ax2 = fmaf(d2.x, w2, ax2); ay2 = fmaf(d2.y, w2, ay2);
            ax3 = fmaf(d3.x, w3, ax3); ay3 = fmaf(d3.y, w3, ay3);
        }
        for (; j < end; j += 2) {
            unsigned p = pair[j];
            unsigned hv = *reinterpret_cast<const unsigned short*>(&h[(size_t)(p & 0xffffu) * 64 + c]);
            f32x2 d = fp8x2f(hv);
            float w = bf_hi(p);
            ax0 = fmaf(d.x, w, ax0); ay0 = fmaf(d.y, w, ay0);
        }
        float ax = (ax0 + ax1) + (ax2 + ax3);
        float ay = (ay0 + ay1) + (ay2 + ay3);
        ax += __shfl_xor(ax, 32);
        ay += __shfl_xor(ay, 32);
        if (half == 0) {
            unsigned pk = (unsigned)f2bf(ax) | ((unsigned)f2bf(ay) << 16);
            *reinterpret_cast<unsigned*>(&agg[(size_t)node * 64 + c]) = pk;
        }
    }
}

// ---- layer-1 dense via MFMA 16x16x32 bf16, both relations fused ----
__global__ __launch_bounds__(256) void dense64_2(
        const unsigned short* __restrict__ aggA, const float* __restrict__ rinA,
        const unsigned short* __restrict__ wtA, const float* __restrict__ bA,
        unsigned short* __restrict__ outA,
        const unsigned short* __restrict__ aggB, const float* __restrict__ rinB,
        const unsigned short* __restrict__ wtB, const float* __restrict__ bB,
        unsigned short* __restrict__ outB, int n) {
    constexpr int K = 64, NCH = 2;
    const int rel = blockIdx.x >= DGRID;
    const int bid = rel ? blockIdx.x - DGRID : blockIdx.x;
    const unsigned short* __restrict__ agg = rel ? aggB : aggA;
    const float* __restrict__ rin = rel ? rinB : rinA;
    const unsigned short* __restrict__ wt = rel ? wtB : wtA;
    const float* __restrict__ b = rel ? bB : bA;
    unsigned short* __restrict__ outbf = rel ? outB : outA;

    const int wave = threadIdx.x >> 6;
    const int lane = threadIdx.x & 63;
    const int lrow = lane & 15;
    const int kgrp = lane >> 4;
    const int c0   = wave * 32;

    short8 bfr[2][NCH];
#pragma unroll
    for (int t = 0; t < 2; ++t)
#pragma unroll
        for (int ch = 0; ch < NCH; ++ch)
            bfr[t][ch] = *reinterpret_cast<const short8*>(
                &wt[(size_t)(c0 + t * 16 + lrow) * K + ch * 32 + kgrp * 8]);

    const float bias0 = b[c0 + lrow], bias1 = b[c0 + 16 + lrow];
    const int nstrip = n >> 4;
    for (int s = bid; s < nstrip; s += DGRID) {
        const int r0 = s << 4;
        f32x4 d0 = {0.f, 0.f, 0.f, 0.f}, d1 = {0.f, 0.f, 0.f, 0.f};
#pragma unroll
        for (int ch = 0; ch < NCH; ++ch) {
            short8 af = *reinterpret_cast<const short8*>(
                &agg[(size_t)(r0 + lrow) * K + ch * 32 + kgrp * 8]);
            d0 = __builtin_amdgcn_mfma_f32_16x16x32_bf16(af, bfr[0][ch], d0, 0, 0, 0);
            d1 = __builtin_amdgcn_mfma_f32_16x16x32_bf16(af, bfr[1][ch], d1, 0, 0, 0);
        }
#pragma unroll
        for (int i = 0; i < 4; ++i) {          // C/D: col=lane&15, row=(lane>>4)*4+i
            const int row = r0 + kgrp * 4 + i;
            const float rv = rin[row];
            outbf[(size_t)row * DH + c0 + lrow]      = f2bf(fmaxf(fmaf(rv, d0[i], bias0), 0.f));
            outbf[(size_t)row * DH + c0 + 16 + lrow] = f2bf(fmaxf(fmaf(rv, d1[i], bias1), 0.f));
        }
    }
}

// ---- h1t = h1 @ W1 -> fp8 tables (pre-transform; both relations fused) ----
__global__ __launch_bounds__(256) void h1t_gemm2(
        const unsigned short* __restrict__ hA, const unsigned short* __restrict__ wtA,
        uint8_t* __restrict__ htA,
        const unsigned short* __restrict__ hB, const unsigned short* __restrict__ wtB,
        uint8_t* __restrict__ htB, int n) {
    constexpr int K = 128, NCH = 4;
    const int rel = blockIdx.x >= DGRID;
    const int bid = rel ? blockIdx.x - DGRID : blockIdx.x;
    const unsigned short* __restrict__ h = rel ? hB : hA;
    const unsigned short* __restrict__ wt = rel ? wtB : wtA;
    uint8_t* __restrict__ ht = rel ? htB : htA;

    const int wave = threadIdx.x >> 6;
    const int lane = threadIdx.x & 63;
    const int lrow = lane & 15;
    const int kgrp = lane >> 4;
    const int c0   = wave * 32;

    short8 bfr[2][NCH];
#pragma unroll
    for (int t = 0; t < 2; ++t)
#pragma unroll
        for (int ch = 0; ch < NCH; ++ch)
            bfr[t][ch] = *reinterpret_cast<const short8*>(
                &wt[(size_t)(c0 + t * 16 + lrow) * K + ch * 32 + kgrp * 8]);

    const int nstrip = n >> 4;
    for (int s = bid; s < nstrip; s += DGRID) {
        const int r0 = s << 4;
        f32x4 d0 = {0.f, 0.f, 0.f, 0.f}, d1 = {0.f, 0.f, 0.f, 0.f};
#pragma unroll
        for (int ch = 0; ch < NCH; ++ch) {
            short8 af = *reinterpret_cast<const short8*>(
                &h[(size_t)(r0 + lrow) * K + ch * 32 + kgrp * 8]);
            d0 = __builtin_amdgcn_mfma_f32_16x16x32_bf16(af, bfr[0][ch], d0, 0, 0, 0);
            d1 = __builtin_amdgcn_mfma_f32_16x16x32_bf16(af, bfr[1][ch], d1, 0, 0, 0);
        }
#pragma unroll
        for (int i = 0; i < 4; ++i) {
            const int row = r0 + kgrp * 4 + i;
            ht[(size_t)row * DH + c0 + lrow]      = f2fp8(d0[i]);
            ht[(size_t)row * DH + c0 + 16 + lrow] = f2fp8(d1[i]);
        }
    }
}

// ---- final gather: out-row = relu(rin*(sum_e w*ht[src]) + b), fused mean-pool ----
__global__ __launch_bounds__(256) void gather_final(
        const uint8_t* __restrict__ htA, const int* __restrict__ ptrA,
        const unsigned* __restrict__ pairA, const float* __restrict__ rinA,
        const float* __restrict__ bA,
        const uint8_t* __restrict__ htB, const int* __restrict__ ptrB,
        const unsigned* __restrict__ pairB, const float* __restrict__ rinB,
        const float* __restrict__ bB,
        float* __restrict__ partsum, int n, float invn) {
    const int rel  = blockIdx.x >= GGRID;
    const int bid  = rel ? blockIdx.x - GGRID : blockIdx.x;
    const uint8_t* __restrict__ ht = rel ? htB : htA;
    const int* __restrict__ ptr  = rel ? ptrB : ptrA;
    const unsigned* __restrict__ pair = rel ? pairB : pairA;
    const float* __restrict__ rin = rel ? rinB : rinA;
    const float* __restrict__ b   = rel ? bB : bA;

    const int gw   = (bid * blockDim.x + threadIdx.x) >> 6;
    const int nw   = (GGRID * blockDim.x) >> 6;
    const int lane = threadIdx.x & 63;
    const int c    = lane << 1;                 // cols c, c+1 (byte offsets too)
    const float bias0 = b[c], bias1 = b[c + 1];
    float m0 = 0.f, m1 = 0.f;

    for (int node = gw; node < n; node += nw) {
        const int beg = ptr[node], end = ptr[node + 1];
        float ax[8], ay[8];
#pragma unroll
        for (int u = 0; u < 8; ++u) { ax[u] = 0.f; ay[u] = 0.f; }
        int j = beg;
        for (; j + 7 < end; j += 8) {
            unsigned p[8]; unsigned hv[8];
#pragma unroll
            for (int u = 0; u < 8; ++u) p[u] = pair[j + u];
#pragma unroll
            for (int u = 0; u < 8; ++u)
                hv[u] = *reinterpret_cast<const unsigned short*>(&ht[(size_t)(p[u] & 0xffffu) * 128 + c]);
#pragma unroll
            for (int u = 0; u < 8; ++u) {
                f32x2 d = fp8x2f(hv[u]);
                float w = bf_hi(p[u]);
                ax[u] = fmaf(d.x, w, ax[u]);
                ay[u] = fmaf(d.y, w, ay[u]);
            }
        }
        for (; j < end; ++j) {
            unsigned p = pair[j];
            unsigned hv = *reinterpret_cast<const unsigned short*>(&ht[(size_t)(p & 0xffffu) * 128 + c]);
            f32x2 d = fp8x2f(hv);
            float w = bf_hi(p);
            ax[0] = fmaf(d.x, w, ax[0]); ay[0] = fmaf(d.y, w, ay[0]);
        }
        float accx = ((ax[0] + ax[1]) + (ax[2] + ax[3])) + ((ax[4] + ax[5]) + (ax[6] + ax[7]));
        float accy = ((ay[0] + ay[1]) + (ay[2] + ay[3])) + ((ay[4] + ay[5]) + (ay[6] + ay[7]));
        const float rv = rin[node];
        m0 += fmaxf(fmaf(rv, accx, bias0), 0.f);
        m1 += fmaxf(fmaf(rv, accy, bias1), 0.f);
    }

    __shared__ float red[512];
    red[threadIdx.x] = m0;
    red[256 + threadIdx.x] = m1;
    __syncthreads();
    if (threadIdx.x < 64) {
        float s0 = red[threadIdx.x] + red[threadIdx.x + 64] + red[threadIdx.x + 128] + red[threadIdx.x + 192];
        float s1 = red[256 + threadIdx.x] + red[256 + threadIdx.x + 64]
                 + red[256 + threadIdx.x + 128] + red[256 + threadIdx.x + 192];
        float* part = partsum + (size_t)blockIdx.x * DH;
        part[2 * threadIdx.x]     = s0 * invn;
        part[2 * threadIdx.x + 1] = s1 * invn;
    }
}

// ---- sum partial rows into out[0..127] ----
__global__ void reduce_out(const float* __restrict__ partial, float* __restrict__ out, int nrows) {
    const int t = threadIdx.x;                 // 128
    const int per = nrows / gridDim.x;
    const int b0 = blockIdx.x * per;
    float s = 0.f;
    for (int b = b0; b < b0 + per; ++b) s += partial[(size_t)b * DH + t];
    atomicAdd(&out[t], s);
}

extern "C" void kernel_launch(void* const* d_in, const int* in_sizes, int n_in,
                              void* d_out, int out_size, void* d_ws, size_t ws_size,
                              hipStream_t stream) {
    const float* feat_row = (const float*)d_in[0];
    const float* feat_col = (const float*)d_in[1];
    const int*   src_rc   = (const int*)d_in[2];
    const int*   dst_rc   = (const int*)d_in[3];
    const float* w_rc     = (const float*)d_in[4];
    const int*   src_cr   = (const int*)d_in[5];
    const int*   dst_cr   = (const int*)d_in[6];
    const float* w_cr     = (const float*)d_in[7];
    const float* W0_rc    = (const float*)d_in[8];
    const float* b0_rc    = (const float*)d_in[9];
    const float* W0_cr    = (const float*)d_in[10];
    const float* b0_cr    = (const float*)d_in[11];
    const float* W1_rc    = (const float*)d_in[12];
    const float* b1_rc    = (const float*)d_in[13];
    const float* W1_cr    = (const float*)d_in[14];
    const float* b1_cr    = (const float*)d_in[15];
    const int E = in_sizes[2];
    float* out = (float*)d_out;

    // ---- workspace layout (~75 MB) ----
    int*   cnt     = (int*)d_ws;                        // 200000
    float* norms   = (float*)(cnt + 200000);            // 200000
    int*   ptr_rc  = (int*)(norms + 200000);            // 50004
    int*   ptr_cr  = ptr_rc + 50004;                    // 50004
    int*   bsum    = ptr_cr + 50004;                    // 200
    int*   cbase   = bsum + 200;                        // 216 (pad)
    unsigned* pair_rc = (unsigned*)(cbase + 216);       // E
    unsigned* pair_cr = pair_rc + E;                    // E
    unsigned short* agg_col = (unsigned short*)(pair_cr + E);       // 50000*64 bf16
    unsigned short* agg_row = agg_col + (size_t)NCOL * 64;          // 50000*64 bf16
    uint8_t* f8_row = (uint8_t*)(agg_row + (size_t)NROW * 64);      // 50000*64 fp8
    uint8_t* f8_col = f8_row + (size_t)NROW * 64;                   // 50000*64 fp8
    unsigned short* h_col1 = (unsigned short*)(f8_col + (size_t)NCOL * 64); // 50000*128 bf16
    unsigned short* h_row1 = h_col1 + (size_t)NCOL * DH;                    // 50000*128 bf16
    uint8_t* ht_row = (uint8_t*)(h_row1 + (size_t)NROW * DH);       // 50000*128 fp8
    uint8_t* ht_col = ht_row + (size_t)NROW * DH;                   // 50000*128 fp8
    float* partsum = (float*)(ht_col + (size_t)NCOL * DH);          // 2*GGRID*128
    unsigned short* wt = (unsigned short*)(partsum + (size_t)2 * GGRID * DH); // 49152
    // hist/fill partial (51.2 MB) aliases agg_col..ht region (dead during CSR build)
    int* partial = (int*)agg_col;

    float* r_out_rc = norms;
    float* r_in_rc  = norms + NROW;
    float* r_out_cr = norms + NROW + NCOL;
    float* r_in_cr  = norms + NROW + 2 * NCOL;

    unsigned short* wt0_rc = wt;
    unsigned short* wt0_cr = wt + 8192;
    unsigned short* wt1_rc = wt + 16384;
    unsigned short* wt1_cr = wt + 32768;

    // ---- CSR build (partial alias live here) ----
    hist_lds<<<16 * HBLK, 512, 0, stream>>>(src_rc, dst_rc, src_cr, dst_cr, partial, E);
    reduce_norms2<<<512, 256, 0, stream>>>(partial, cnt, norms);
    scanA<<<200, 256, 0, stream>>>(cnt, bsum);
    scanB<<<1, 256, 0, stream>>>(bsum, cbase);
    scanC<<<200, 512, 0, stream>>>(cnt, cbase, ptr_rc, ptr_cr, E);
    block_starts<<<400, 256, 0, stream>>>(partial, ptr_rc, ptr_cr);
    csr_fill_sorted<<<8 * HBLK, 512, 0, stream>>>(
        src_rc, dst_rc, w_rc, r_out_rc, pair_rc,
        src_cr, dst_cr, w_cr, r_out_cr, pair_cr, partial, E);

    // ---- fp8 feature tables + bf16 weights (partial now dead) ----
    prep_tables<<<2048, 256, 0, stream>>>((const float4*)feat_row, (const float4*)feat_col,
                                          (unsigned*)f8_row, (unsigned*)f8_col, NROW * 64 / 4,
                                          W0_rc, W0_cr, W1_rc, W1_cr, wt);

    // ---- layer 1 ----
    gather64_2<<<2 * GGRID, 256, 0, stream>>>(f8_row, ptr_rc, pair_rc, agg_col,
                                              f8_col, ptr_cr, pair_cr, agg_row, NCOL);
    dense64_2<<<2 * DGRID, 256, 0, stream>>>(agg_col, r_in_rc, wt0_rc, b0_rc, h_col1,
                                             agg_row, r_in_cr, wt0_cr, b0_cr, h_row1, NCOL);

    // ---- layer 2: pre-transform h1@W1 -> fp8, then fused gather+relu+mean ----
    h1t_gemm2<<<2 * DGRID, 256, 0, stream>>>(h_row1, wt1_rc, ht_row,
                                             h_col1, wt1_cr, ht_col, NROW);
    hipMemsetAsync(out, 0, DH * sizeof(float), stream);
    gather_final<<<2 * GGRID, 256, 0, stream>>>(
        ht_row, ptr_rc, pair_rc, r_in_rc, b1_rc,
        ht_col, ptr_cr, pair_cr, r_in_cr, b1_cr,
        partsum, NCOL, 1.0f / NCOL);
    reduce_out<<<32, 128, 0, stream>>>(partsum, out, 2 * GGRID);
}

// Round 13
// 332.914 us; speedup vs baseline: 2.2750x; 1.0075x over previous
//
#include <hip/hip_runtime.h>
#include <stdint.h>

constexpr int NROW = 50000;
constexpr int NCOL = 50000;
constexpr int DH   = 128;
constexpr int NTAB = 200000;   // [out_rc(NROW) | in_rc(NCOL) | out_cr(NCOL) | in_cr(NROW)]
constexpr int HB   = 12500;    // bins per section (quarter table), 50 KB LDS
constexpr int HBLK = 64;       // blocks per section
constexpr int DGRID = 1250;    // dense blocks per relation
constexpr int GGRID = 2048;    // gather blocks per relation
constexpr int CH    = 500;     // scan chunk size (100 chunks per table)

typedef __attribute__((ext_vector_type(8))) short short8;
typedef __attribute__((ext_vector_type(4))) float f32x4;
typedef __attribute__((ext_vector_type(2))) float f32x2;

__device__ __forceinline__ float bf_hi(unsigned u) { return __uint_as_float(u & 0xffff0000u); }
__device__ __forceinline__ unsigned short f2bf(float f) {   // RNE
    unsigned u = __float_as_uint(f);
    return (unsigned short)((u + 0x7fffu + ((u >> 16) & 1u)) >> 16);
}

// ---- fp8 OCP e4m3fn encode (RNE, clamp 448, subnormal-aware) ----
__device__ __forceinline__ unsigned char f2fp8(float f) {
    unsigned b = __float_as_uint(f);
    unsigned s = (b >> 24) & 0x80u;
    unsigned mag = b & 0x7fffffffu;
    if (mag >= 0x43e00000u) return (unsigned char)(s | 0x7eu);   // clamp to ±448
    unsigned r = mag + 0x7ffffu + ((mag >> 20) & 1u);
    int e = (int)(r >> 23) - 120;
    if (e < 1) {                                                  // subnormal: m * 2^-9
        float af = __uint_as_float(mag);
        unsigned m = (unsigned)(af * 512.f + 0.5f);
        if (m > 8u) m = 8u;
        return (unsigned char)(s | m);
    }
    return (unsigned char)(s | (unsigned)(e << 3) | ((r >> 20) & 7u));
}

// ---- fp8 x2 decode (HW cvt if available) ----
#if defined(__has_builtin) && __has_builtin(__builtin_amdgcn_cvt_pk_f32_fp8)
__device__ __forceinline__ f32x2 fp8x2f(unsigned v) {
    return __builtin_amdgcn_cvt_pk_f32_fp8((int)v, false);
}
#else
__device__ __forceinline__ float fp8_1(unsigned u) {
    unsigned s = (u & 0x80u) << 24, em = u & 0x7fu;
    if (em >= 8u) return __uint_as_float(s | ((em + 960u) << 20));
    float v = (float)em * 0.001953125f;
    return (u & 0x80u) ? -v : v;
}
__device__ __forceinline__ f32x2 fp8x2f(unsigned v) {
    f32x2 r; r.x = fp8_1(v & 0xffu); r.y = fp8_1((v >> 8) & 0xffu); return r;
}
#endif

// ---- degree histograms via LDS privatization; u16 partials (max/block 18750) ----
__global__ __launch_bounds__(512) void hist_lds(
        const int* __restrict__ s_rc, const int* __restrict__ d_rc,
        const int* __restrict__ s_cr, const int* __restrict__ d_cr,
        unsigned short* __restrict__ partial, int E) {
    __shared__ int h[HB];
    const int sec = blockIdx.x >> 6;           // 0..15
    const int blk = blockIdx.x & (HBLK - 1);
    const int tab = sec >> 2;                  // 0..3 -> array
    const int lo  = (sec & 3) * HB;
    const int* __restrict__ arr = (tab == 0) ? s_rc : (tab == 1) ? d_rc
                                 : (tab == 2) ? s_cr : d_cr;
    for (int i = threadIdx.x; i < HB; i += blockDim.x) h[i] = 0;
    __syncthreads();
    const int stride = HBLK * blockDim.x;
    for (int i = blk * blockDim.x + threadIdx.x; i < E; i += stride) {
        int id = arr[i] - lo;
        if ((unsigned)id < (unsigned)HB) atomicAdd(&h[id], 1);   // LDS atomic
    }
    __syncthreads();
    unsigned short* __restrict__ out = partial + ((size_t)sec * HBLK + blk) * HB;
    for (int i = threadIdx.x; i < HB; i += blockDim.x) out[i] = (unsigned short)h[i];
}

// ---- reduce HBLK u16 partials/section -> cnt + norms ----
__global__ void reduce_norms2(const unsigned short* __restrict__ partial, int* __restrict__ cnt,
                              float* __restrict__ norms) {
    int stride = gridDim.x * blockDim.x;
    for (int i = blockIdx.x * blockDim.x + threadIdx.x; i < NTAB; i += stride) {
        int t = i / 50000;
        int r = i - t * 50000;
        int q = r / HB;
        int j = r - q * HB;
        const unsigned short* __restrict__ p = partial + ((size_t)(t * 4 + q) * HBLK) * HB + j;
        int s = 0;
#pragma unroll
        for (int b = 0; b < HBLK; ++b) s += p[(size_t)b * HB];
        cnt[i] = s;
        norms[i] = 1.0f / sqrtf((float)max(s, 1));
    }
}

// ---- parallel exclusive scan of the two dst-count tables, 3 phases ----
__global__ __launch_bounds__(256) void scanA(const int* __restrict__ cnt, int* __restrict__ bsum) {
    __shared__ int red[256];
    const int c = blockIdx.x;
    const int* __restrict__ cbl = cnt + ((c >= 100) ? 150000 : 50000);
    const int j0 = (c % 100) * CH;
    int s = 0;
    for (int i = threadIdx.x; i < CH; i += 256) s += cbl[j0 + i];
    red[threadIdx.x] = s;
    __syncthreads();
    for (int off = 128; off > 0; off >>= 1) {
        if (threadIdx.x < off) red[threadIdx.x] += red[threadIdx.x + off];
        __syncthreads();
    }
    if (threadIdx.x == 0) bsum[c] = red[0];
}

__global__ void scanB(const int* __restrict__ bsum, int* __restrict__ cbase) {
    __shared__ int b[200];
    for (int i = threadIdx.x; i < 200; i += blockDim.x) b[i] = bsum[i];
    __syncthreads();
    if (threadIdx.x < 2) {
        int run = 0;
        const int o = threadIdx.x * 100;
        for (int k = 0; k < 100; ++k) { cbase[o + k] = run; run += b[o + k]; }
    }
}

__global__ __launch_bounds__(512) void scanC(const int* __restrict__ cnt,
                                             const int* __restrict__ cbase,
                                             int* __restrict__ ptr_rc, int* __restrict__ ptr_cr,
                                             int E) {
    __shared__ int buf[512];
    const int c = blockIdx.x;
    const int table = (c >= 100);
    const int* __restrict__ cbl = cnt + (table ? 150000 : 50000);
    int* __restrict__ ptr = table ? ptr_cr : ptr_rc;
    const int j0 = (c % 100) * CH;
    const int t = threadIdx.x;
    const int v = (t < CH) ? cbl[j0 + t] : 0;
    buf[t] = v;
    __syncthreads();
    for (int off = 1; off < 512; off <<= 1) {
        int tmp = (t >= off) ? buf[t - off] : 0;
        __syncthreads();
        buf[t] += tmp;
        __syncthreads();
    }
    if (t < CH) ptr[j0 + t] = cbase[c] + buf[t] - v;
    if ((c % 100) == 99 && t == 0) ptr[50000] = E;
}

// ---- dst-section u16 partials -> absolute int block start positions ----
// bstart[fsec][blk][bin], fsec = rel*4+q in 0..7
__global__ void block_starts(const unsigned short* __restrict__ partial, int* __restrict__ bstart,
                             const int* __restrict__ ptr_rc, const int* __restrict__ ptr_cr) {
    int stride = gridDim.x * blockDim.x;
    for (int i = blockIdx.x * blockDim.x + threadIdx.x; i < 8 * HB; i += stride) {
        int fsec = i / HB;                 // 0..7 = (rel, quarter)
        int j = i - fsec * HB;
        int rel = fsec >> 2, q = fsec & 3;
        int histsec = rel * 8 + 4 + q;     // dst tab = rel*2+1
        const int* __restrict__ ptr = rel ? ptr_cr : ptr_rc;
        int run = ptr[q * HB + j];
        const unsigned short* __restrict__ p = partial + ((size_t)histsec * HBLK) * HB + j;
        int* __restrict__ o = bstart + ((size_t)fsec * HBLK) * HB + j;
#pragma unroll
        for (int b = 0; b < HBLK; ++b) {
            o[(size_t)b * HB] = run;
            run += p[(size_t)b * HB];
        }
    }
}

// ---- CSR fill, XCD-affine: all blocks of a section share one XCD (blockIdx%8) ----
// so scattered 4B pair stores merge in that XCD's write-back L2.
__global__ __launch_bounds__(512) void csr_fill_sorted(
        const int* __restrict__ sA, const int* __restrict__ dA,
        const float* __restrict__ wA, const float* __restrict__ routA, unsigned* __restrict__ pairA,
        const int* __restrict__ sB, const int* __restrict__ dB,
        const float* __restrict__ wB, const float* __restrict__ routB, unsigned* __restrict__ pairB,
        const int* __restrict__ bstart, int E) {
    __shared__ int offs[HB];
    const int fsec = blockIdx.x & 7;           // section -> XCD (blockIdx % 8 round-robin)
    const int blk  = blockIdx.x >> 3;          // 0..63, same edge slice as hist's blk
    const int rel = fsec >> 2, q = fsec & 3;
    const int lo = q * HB;
    const int* __restrict__ src  = rel ? sB : sA;
    const int* __restrict__ dst  = rel ? dB : dA;
    const float* __restrict__ w  = rel ? wB : wA;
    const float* __restrict__ ro = rel ? routB : routA;
    unsigned* __restrict__ pair  = rel ? pairB : pairA;
    const int* __restrict__ bs = bstart + ((size_t)fsec * HBLK + blk) * HB;
    for (int i = threadIdx.x; i < HB; i += blockDim.x) offs[i] = bs[i];
    __syncthreads();
    const int stride = HBLK * blockDim.x;
    for (int i = blk * blockDim.x + threadIdx.x; i < E; i += stride) {
        int id = dst[i] - lo;
        if ((unsigned)id < (unsigned)HB) {
            int pos = atomicAdd(&offs[id], 1);            // LDS atomic
            int s = src[i];
            pair[pos] = (unsigned)s | ((unsigned)f2bf(w[i] * ro[s]) << 16);
        }
    }
}

// ---- fp32 -> fp8 feature tables + transposed bf16 weights, one launch ----
__global__ void prep_tables(const float4* __restrict__ fr, const float4* __restrict__ fc,
                            unsigned* __restrict__ f8r, unsigned* __restrict__ f8c, int nq,
                            const float* __restrict__ W0a, const float* __restrict__ W0b,
                            const float* __restrict__ W1a, const float* __restrict__ W1b,
                            unsigned short* __restrict__ wt) {
    const int total = 2 * nq + 49152;
    int stride = gridDim.x * blockDim.x;
    for (int i = blockIdx.x * blockDim.x + threadIdx.x; i < total; i += stride) {
        if (i < 2 * nq) {
            bool second = i >= nq;
            int k = second ? i - nq : i;
            float4 v = second ? fc[k] : fr[k];
            unsigned o = (unsigned)f2fp8(v.x) | ((unsigned)f2fp8(v.y) << 8)
                       | ((unsigned)f2fp8(v.z) << 16) | ((unsigned)f2fp8(v.w) << 24);
            if (second) f8c[k] = o; else f8r[k] = o;
        } else {
            int j = i - 2 * nq;
            const float* W; int K, base;
            if (j < 8192)       { W = W0a; K = 64;  base = 0; }
            else if (j < 16384) { W = W0b; K = 64;  base = 8192;  j -= 8192; }
            else if (j < 32768) { W = W1a; K = 128; base = 16384; j -= 16384; }
            else                { W = W1b; K = 128; base = 32768; j -= 32768; }
            int n = j / K, k = j - n * K;
            wt[base + n * K + k] = f2bf(W[k * DH + n]);
        }
    }
}

// ---- D=64 gather from fp8 tables, XCD-affine relation split (table L2-resident) ----
__global__ void gather64_2(const uint8_t* __restrict__ hA, const int* __restrict__ ptrA,
                           const unsigned* __restrict__ pairA, unsigned short* __restrict__ aggA,
                           const uint8_t* __restrict__ hB, const int* __restrict__ ptrB,
                           const unsigned* __restrict__ pairB, unsigned short* __restrict__ aggB,
                           int n) {
    const int low  = blockIdx.x & 7;
    const int rel  = low >> 2;                  // XCDs 0-3: rel A, 4-7: rel B
    const int bid  = (blockIdx.x >> 3) * 4 + (low & 3);   // 0..GGRID-1
    const uint8_t* __restrict__ h = rel ? hB : hA;
    const int* __restrict__ ptr  = rel ? ptrB : ptrA;
    const unsigned* __restrict__ pair = rel ? pairB : pairA;
    unsigned short* __restrict__ agg  = rel ? aggB : aggA;
    const int gw   = (bid * blockDim.x + threadIdx.x) >> 6;
    const int nw   = (GGRID * blockDim.x) >> 6;
    const int lane = threadIdx.x & 63;
    const int half = lane >> 5;
    const int c    = (lane & 31) << 1;          // column pair 0..62
    for (int node = gw; node < n; node += nw) {
        const int beg = ptr[node], end = ptr[node + 1];
        float ax0 = 0.f, ay0 = 0.f, ax1 = 0.f, ay1 = 0.f;
        float ax2 = 0.f, ay2 = 0.f, ax3 = 0.f, ay3 = 0.f;
        int j = beg + half;
        for (; j + 6 < end; j += 8) {
            unsigned p0 = pair[j], p1 = pair[j + 2], p2 = pair[j + 4], p3 = pair[j + 6];
            unsigned h0 = *reinterpret_cast<const unsigned short*>(&h[(size_t)(p0 & 0xffffu) * 64 + c]);
            unsigned h1 = *reinterpret_cast<const unsigned short*>(&h[(size_t)(p1 & 0xffffu) * 64 + c]);
            unsigned h2 = *reinterpret_cast<const unsigned short*>(&h[(size_t)(p2 & 0xffffu) * 64 + c]);
            unsigned h3 = *reinterpret_cast<const unsigned short*>(&h[(size_t)(p3 & 0xffffu) * 64 + c]);
            f32x2 d0 = fp8x2f(h0), d1 = fp8x2f(h1), d2 = fp8x2f(h2), d3 = fp8x2f(h3);
            float w0 = bf_hi(p0), w1 = bf_hi(p1), w2 = bf_hi(p2), w3 = bf_hi(p3);
            ax0 = fmaf(d0.x, w0, ax0); ay0 = fmaf(d0.y, w0, ay0);
            ax1 = fmaf(d1.x, w1, ax1); ay1 = fmaf(d1.y, w1, ay1);
            ax2 = fmaf(d2.x, w2, ax2); ay2 = fmaf(d2.y, w2, ay2);
            ax3 = fmaf(d3.x, w3, ax3); ay3 = fmaf(d3.y, w3, ay3);
        }
        for (; j < end; j += 2) {
            unsigned p = pair[j];
            unsigned hv = *reinterpret_cast<const unsigned short*>(&h[(size_t)(p & 0xffffu) * 64 + c]);
            f32x2 d = fp8x2f(hv);
            float w = bf_hi(p);
            ax0 = fmaf(d.x, w, ax0); ay0 = fmaf(d.y, w, ay0);
        }
        float ax = (ax0 + ax1) + (ax2 + ax3);
        float ay = (ay0 + ay1) + (ay2 + ay3);
        ax += __shfl_xor(ax, 32);
        ay += __shfl_xor(ay, 32);
        if (half == 0) {
            unsigned pk = (unsigned)f2bf(ax) | ((unsigned)f2bf(ay) << 16);
            *reinterpret_cast<unsigned*>(&agg[(size_t)node * 64 + c]) = pk;
        }
    }
}

// ---- layer-1 dense via MFMA 16x16x32 bf16, both relations fused ----
__global__ __launch_bounds__(256) void dense64_2(
        const unsigned short* __restrict__ aggA, const float* __restrict__ rinA,
        const unsigned short* __restrict__ wtA, const float* __restrict__ bA,
        unsigned short* __restrict__ outA,
        const unsigned short* __restrict__ aggB, const float* __restrict__ rinB,
        const unsigned short* __restrict__ wtB, const float* __restrict__ bB,
        unsigned short* __restrict__ outB, int n) {
    constexpr int K = 64, NCH = 2;
    const int rel = blockIdx.x >= DGRID;
    const int bid = rel ? blockIdx.x - DGRID : blockIdx.x;
    const unsigned short* __restrict__ agg = rel ? aggB : aggA;
    const float* __restrict__ rin = rel ? rinB : rinA;
    const unsigned short* __restrict__ wt = rel ? wtB : wtA;
    const float* __restrict__ b = rel ? bB : bA;
    unsigned short* __restrict__ outbf = rel ? outB : outA;

    const int wave = threadIdx.x >> 6;
    const int lane = threadIdx.x & 63;
    const int lrow = lane & 15;
    const int kgrp = lane >> 4;
    const int c0   = wave * 32;

    short8 bfr[2][NCH];
#pragma unroll
    for (int t = 0; t < 2; ++t)
#pragma unroll
        for (int ch = 0; ch < NCH; ++ch)
            bfr[t][ch] = *reinterpret_cast<const short8*>(
                &wt[(size_t)(c0 + t * 16 + lrow) * K + ch * 32 + kgrp * 8]);

    const float bias0 = b[c0 + lrow], bias1 = b[c0 + 16 + lrow];
    const int nstrip = n >> 4;
    for (int s = bid; s < nstrip; s += DGRID) {
        const int r0 = s << 4;
        f32x4 d0 = {0.f, 0.f, 0.f, 0.f}, d1 = {0.f, 0.f, 0.f, 0.f};
#pragma unroll
        for (int ch = 0; ch < NCH; ++ch) {
            short8 af = *reinterpret_cast<const short8*>(
                &agg[(size_t)(r0 + lrow) * K + ch * 32 + kgrp * 8]);
            d0 = __builtin_amdgcn_mfma_f32_16x16x32_bf16(af, bfr[0][ch], d0, 0, 0, 0);
            d1 = __builtin_amdgcn_mfma_f32_16x16x32_bf16(af, bfr[1][ch], d1, 0, 0, 0);
        }
#pragma unroll
        for (int i = 0; i < 4; ++i) {          // C/D: col=lane&15, row=(lane>>4)*4+i
            const int row = r0 + kgrp * 4 + i;
            const float rv = rin[row];
            outbf[(size_t)row * DH + c0 + lrow]      = f2bf(fmaxf(fmaf(rv, d0[i], bias0), 0.f));
            outbf[(size_t)row * DH + c0 + 16 + lrow] = f2bf(fmaxf(fmaf(rv, d1[i], bias1), 0.f));
        }
    }
}

// ---- h1t = h1 @ W1 -> fp8 tables (pre-transform; both relations fused) ----
__global__ __launch_bounds__(256) void h1t_gemm2(
        const unsigned short* __restrict__ hA, const unsigned short* __restrict__ wtA,
        uint8_t* __restrict__ htA,
        const unsigned short* __restrict__ hB, const unsigned short* __restrict__ wtB,
        uint8_t* __restrict__ htB, int n) {
    constexpr int K = 128, NCH = 4;
    const int rel = blockIdx.x >= DGRID;
    const int bid = rel ? blockIdx.x - DGRID : blockIdx.x;
    const unsigned short* __restrict__ h = rel ? hB : hA;
    const unsigned short* __restrict__ wt = rel ? wtB : wtA;
    uint8_t* __restrict__ ht = rel ? htB : htA;

    const int wave = threadIdx.x >> 6;
    const int lane = threadIdx.x & 63;
    const int lrow = lane & 15;
    const int kgrp = lane >> 4;
    const int c0   = wave * 32;

    short8 bfr[2][NCH];
#pragma unroll
    for (int t = 0; t < 2; ++t)
#pragma unroll
        for (int ch = 0; ch < NCH; ++ch)
            bfr[t][ch] = *reinterpret_cast<const short8*>(
                &wt[(size_t)(c0 + t * 16 + lrow) * K + ch * 32 + kgrp * 8]);

    const int nstrip = n >> 4;
    for (int s = bid; s < nstrip; s += DGRID) {
        const int r0 = s << 4;
        f32x4 d0 = {0.f, 0.f, 0.f, 0.f}, d1 = {0.f, 0.f, 0.f, 0.f};
#pragma unroll
        for (int ch = 0; ch < NCH; ++ch) {
            short8 af = *reinterpret_cast<const short8*>(
                &h[(size_t)(r0 + lrow) * K + ch * 32 + kgrp * 8]);
            d0 = __builtin_amdgcn_mfma_f32_16x16x32_bf16(af, bfr[0][ch], d0, 0, 0, 0);
            d1 = __builtin_amdgcn_mfma_f32_16x16x32_bf16(af, bfr[1][ch], d1, 0, 0, 0);
        }
#pragma unroll
        for (int i = 0; i < 4; ++i) {
            const int row = r0 + kgrp * 4 + i;
            ht[(size_t)row * DH + c0 + lrow]      = f2fp8(d0[i]);
            ht[(size_t)row * DH + c0 + 16 + lrow] = f2fp8(d1[i]);
        }
    }
}

// ---- final gather: out-row = relu(rin*(sum_e w*ht[src]) + b), fused mean-pool ----
__global__ __launch_bounds__(256) void gather_final(
        const uint8_t* __restrict__ htA, const int* __restrict__ ptrA,
        const unsigned* __restrict__ pairA, const float* __restrict__ rinA,
        const float* __restrict__ bA,
        const uint8_t* __restrict__ htB, const int* __restrict__ ptrB,
        const unsigned* __restrict__ pairB, const float* __restrict__ rinB,
        const float* __restrict__ bB,
        float* __restrict__ partsum, int n, float invn) {
    const int low  = blockIdx.x & 7;
    const int rel  = low >> 2;                  // XCDs 0-3: rel A, 4-7: rel B
    const int bid  = (blockIdx.x >> 3) * 4 + (low & 3);
    const uint8_t* __restrict__ ht = rel ? htB : htA;
    const int* __restrict__ ptr  = rel ? ptrB : ptrA;
    const unsigned* __restrict__ pair = rel ? pairB : pairA;
    const float* __restrict__ rin = rel ? rinB : rinA;
    const float* __restrict__ b   = rel ? bB : bA;

    const int gw   = (bid * blockDim.x + threadIdx.x) >> 6;
    const int nw   = (GGRID * blockDim.x) >> 6;
    const int lane = threadIdx.x & 63;
    const int c    = lane << 1;                 // cols c, c+1 (byte offsets too)
    const float bias0 = b[c], bias1 = b[c + 1];
    float m0 = 0.f, m1 = 0.f;

    for (int node = gw; node < n; node += nw) {
        const int beg = ptr[node], end = ptr[node + 1];
        float ax[8], ay[8];
#pragma unroll
        for (int u = 0; u < 8; ++u) { ax[u] = 0.f; ay[u] = 0.f; }
        int j = beg;
        for (; j + 7 < end; j += 8) {
            unsigned p[8]; unsigned hv[8];
#pragma unroll
            for (int u = 0; u < 8; ++u) p[u] = pair[j + u];
#pragma unroll
            for (int u = 0; u < 8; ++u)
                hv[u] = *reinterpret_cast<const unsigned short*>(&ht[(size_t)(p[u] & 0xffffu) * 128 + c]);
#pragma unroll
            for (int u = 0; u < 8; ++u) {
                f32x2 d = fp8x2f(hv[u]);
                float w = bf_hi(p[u]);
                ax[u] = fmaf(d.x, w, ax[u]);
                ay[u] = fmaf(d.y, w, ay[u]);
            }
        }
        for (; j < end; ++j) {
            unsigned p = pair[j];
            unsigned hv = *reinterpret_cast<const unsigned short*>(&ht[(size_t)(p & 0xffffu) * 128 + c]);
            f32x2 d = fp8x2f(hv);
            float w = bf_hi(p);
            ax[0] = fmaf(d.x, w, ax[0]); ay[0] = fmaf(d.y, w, ay[0]);
        }
        float accx = ((ax[0] + ax[1]) + (ax[2] + ax[3])) + ((ax[4] + ax[5]) + (ax[6] + ax[7]));
        float accy = ((ay[0] + ay[1]) + (ay[2] + ay[3])) + ((ay[4] + ay[5]) + (ay[6] + ay[7]));
        const float rv = rin[node];
        m0 += fmaxf(fmaf(rv, accx, bias0), 0.f);
        m1 += fmaxf(fmaf(rv, accy, bias1), 0.f);
    }

    __shared__ float red[512];
    red[threadIdx.x] = m0;
    red[256 + threadIdx.x] = m1;
    __syncthreads();
    if (threadIdx.x < 64) {
        float s0 = red[threadIdx.x] + red[threadIdx.x + 64] + red[threadIdx.x + 128] + red[threadIdx.x + 192];
        float s1 = red[256 + threadIdx.x] + red[256 + threadIdx.x + 64]
                 + red[256 + threadIdx.x + 128] + red[256 + threadIdx.x + 192];
        float* part = partsum + (size_t)blockIdx.x * DH;
        part[2 * threadIdx.x]     = s0 * invn;
        part[2 * threadIdx.x + 1] = s1 * invn;
    }
}

// ---- sum partial rows into out[0..127] ----
__global__ void reduce_out(const float* __restrict__ partial, float* __restrict__ out, int nrows) {
    const int t = threadIdx.x;                 // 128
    const int per = nrows / gridDim.x;
    const int b0 = blockIdx.x * per;
    float s = 0.f;
    for (int b = b0; b < b0 + per; ++b) s += partial[(size_t)b * DH + t];
    atomicAdd(&out[t], s);
}

extern "C" void kernel_launch(void* const* d_in, const int* in_sizes, int n_in,
                              void* d_out, int out_size, void* d_ws, size_t ws_size,
                              hipStream_t stream) {
    const float* feat_row = (const float*)d_in[0];
    const float* feat_col = (const float*)d_in[1];
    const int*   src_rc   = (const int*)d_in[2];
    const int*   dst_rc   = (const int*)d_in[3];
    const float* w_rc     = (const float*)d_in[4];
    const int*   src_cr   = (const int*)d_in[5];
    const int*   dst_cr   = (const int*)d_in[6];
    const float* w_cr     = (const float*)d_in[7];
    const float* W0_rc    = (const float*)d_in[8];
    const float* b0_rc    = (const float*)d_in[9];
    const float* W0_cr    = (const float*)d_in[10];
    const float* b0_cr    = (const float*)d_in[11];
    const float* W1_rc    = (const float*)d_in[12];
    const float* b1_rc    = (const float*)d_in[13];
    const float* W1_cr    = (const float*)d_in[14];
    const float* b1_cr    = (const float*)d_in[15];
    const int E = in_sizes[2];
    float* out = (float*)d_out;

    // ---- workspace layout (~75 MB) ----
    int*   cnt     = (int*)d_ws;                        // 200000
    float* norms   = (float*)(cnt + 200000);            // 200000
    int*   ptr_rc  = (int*)(norms + 200000);            // 50004
    int*   ptr_cr  = ptr_rc + 50004;                    // 50004
    int*   bsum    = ptr_cr + 50004;                    // 200
    int*   cbase   = bsum + 200;                        // 216 (pad)
    unsigned* pair_rc = (unsigned*)(cbase + 216);       // E
    unsigned* pair_cr = pair_rc + E;                    // E
    unsigned short* agg_col = (unsigned short*)(pair_cr + E);       // 50000*64 bf16
    unsigned short* agg_row = agg_col + (size_t)NCOL * 64;          // 50000*64 bf16
    uint8_t* f8_row = (uint8_t*)(agg_row + (size_t)NROW * 64);      // 50000*64 fp8
    uint8_t* f8_col = f8_row + (size_t)NROW * 64;                   // 50000*64 fp8
    unsigned short* h_col1 = (unsigned short*)(f8_col + (size_t)NCOL * 64); // 50000*128 bf16
    unsigned short* h_row1 = h_col1 + (size_t)NCOL * DH;                    // 50000*128 bf16
    uint8_t* ht_row = (uint8_t*)(h_row1 + (size_t)NROW * DH);       // 50000*128 fp8
    uint8_t* ht_col = ht_row + (size_t)NROW * DH;                   // 50000*128 fp8
    float* partsum = (float*)(ht_col + (size_t)NCOL * DH);          // 2*GGRID*128
    unsigned short* wt = (unsigned short*)(partsum + (size_t)2 * GGRID * DH); // 49152
    // CSR-build aliases (dead before gathers/prep): u16 partial (25.6 MB) + int bstart (25.6 MB)
    unsigned short* partial = (unsigned short*)agg_col;             // 16*HBLK*HB u16
    int* bstart = (int*)(partial + (size_t)16 * HBLK * HB);         // 8*HBLK*HB int

    float* r_out_rc = norms;
    float* r_in_rc  = norms + NROW;
    float* r_out_cr = norms + NROW + NCOL;
    float* r_in_cr  = norms + NROW + 2 * NCOL;

    unsigned short* wt0_rc = wt;
    unsigned short* wt0_cr = wt + 8192;
    unsigned short* wt1_rc = wt + 16384;
    unsigned short* wt1_cr = wt + 32768;

    // ---- CSR build (aliases live here) ----
    hist_lds<<<16 * HBLK, 512, 0, stream>>>(src_rc, dst_rc, src_cr, dst_cr, partial, E);
    reduce_norms2<<<512, 256, 0, stream>>>(partial, cnt, norms);
    scanA<<<200, 256, 0, stream>>>(cnt, bsum);
    scanB<<<1, 256, 0, stream>>>(bsum, cbase);
    scanC<<<200, 512, 0, stream>>>(cnt, cbase, ptr_rc, ptr_cr, E);
    block_starts<<<400, 256, 0, stream>>>(partial, bstart, ptr_rc, ptr_cr);
    csr_fill_sorted<<<8 * HBLK, 512, 0, stream>>>(
        src_rc, dst_rc, w_rc, r_out_rc, pair_rc,
        src_cr, dst_cr, w_cr, r_out_cr, pair_cr, bstart, E);

    // ---- fp8 feature tables + bf16 weights (aliases now dead) ----
    prep_tables<<<2048, 256, 0, stream>>>((const float4*)feat_row, (const float4*)feat_col,
                                          (unsigned*)f8_row, (unsigned*)f8_col, NROW * 64 / 4,
                                          W0_rc, W0_cr, W1_rc, W1_cr, wt);

    // ---- layer 1 ----
    gather64_2<<<2 * GGRID, 256, 0, stream>>>(f8_row, ptr_rc, pair_rc, agg_col,
                                              f8_col, ptr_cr, pair_cr, agg_row, NCOL);
    dense64_2<<<2 * DGRID, 256, 0, stream>>>(agg_col, r_in_rc, wt0_rc, b0_rc, h_col1,
                                             agg_row, r_in_cr, wt0_cr, b0_cr, h_row1, NCOL);

    // ---- layer 2: pre-transform h1@W1 -> fp8, then fused gather+relu+mean ----
    h1t_gemm2<<<2 * DGRID, 256, 0, stream>>>(h_row1, wt1_rc, ht_row,
                                             h_col1, wt1_cr, ht_col, NROW);
    hipMemsetAsync(out, 0, DH * sizeof(float), stream);
    gather_final<<<2 * GGRID, 256, 0, stream>>>(
        ht_row, ptr_rc, pair_rc, r_in_rc, b1_rc,
        ht_col, ptr_cr, pair_cr, r_in_cr, b1_cr,
        partsum, NCOL, 1.0f / NCOL);
    reduce_out<<<32, 128, 0, stream>>>(partsum, out, 2 * GGRID);
}